// Round 7
// baseline (148.827 us; speedup 1.0000x reference)
//
#include <hip/hip_runtime.h>
#include <hip/hip_bf16.h>
#include <math.h>

#define B_  4
#define T_  4096
#define C_  1024
#define HS_ 128

using bf16x8 = __attribute__((ext_vector_type(8))) __bf16;
using bf16x4 = __attribute__((ext_vector_type(4))) __bf16;
using f32x4  = __attribute__((ext_vector_type(4))) float;

#define MFMA(a, b, c) __builtin_amdgcn_mfma_f32_16x16x32_bf16(a, b, c, 0, 0, 0)

typedef __attribute__((address_space(1))) const float gfloat;
typedef __attribute__((address_space(3))) float lfloat;

// fast exp2 via v_exp_f32; trailing s_nop covers the 1-wait-state trans hazard
__device__ inline float fexp2(float x) {
  float r;
  asm volatile("v_exp_f32 %0, %1\n\ts_nop 0" : "=v"(r) : "v"(x));
  return r;
}

// ---------------------------------------------------------------------------
// Kernel 1: W fp32 [1024][128] -> Wt bf16 [3][128][1024] via LDS transpose.
// m=0: Wq scaled by 1/sqrt(128) * log2(e)  (exp2-domain softmax).
// ---------------------------------------------------------------------------
__global__ __launch_bounds__(256) void prep_w_kernel(
    const float* __restrict__ Wk, const float* __restrict__ Wq,
    const float* __restrict__ Wv, __bf16* __restrict__ Wt) {
  const int m  = blockIdx.x >> 4;        // 0..2
  const int k0 = (blockIdx.x & 15) * 64; // k-slab base
  const float* W = (m == 0) ? Wq : ((m == 1) ? Wk : Wv);
  const float scale = (m == 0) ? (0.08838834764831845f * 1.4426950408889634f) : 1.0f;
  __shared__ __bf16 tile[128][72];       // [n][k-within-slab], padded
  const int t = threadIdx.x;
#pragma unroll
  for (int p = 0; p < 8; ++p) {
    int e  = p * 1024 + t * 4;
    int r  = e >> 7;                     // 0..63
    int cc = e & 127;
    float4 w = *reinterpret_cast<const float4*>(&W[(size_t)(k0 + r) * HS_ + cc]);
    tile[cc + 0][r] = (__bf16)(w.x * scale);
    tile[cc + 1][r] = (__bf16)(w.y * scale);
    tile[cc + 2][r] = (__bf16)(w.z * scale);
    tile[cc + 3][r] = (__bf16)(w.w * scale);
  }
  __syncthreads();
#pragma unroll
  for (int p = 0; p < 4; ++p) {
    int e  = p * 2048 + t * 8;
    int n  = e >> 6;                     // 0..127
    int kk = e & 63;
    bf16x8 v;
#pragma unroll
    for (int jj = 0; jj < 8; ++jj) v[jj] = tile[n][kk + jj];
    *reinterpret_cast<bf16x8*>(&Wt[((size_t)m * 128 + n) * C_ + k0 + kk]) = v;
  }
}

__device__ inline bf16x8 cvt8p(float4 u, float4 v) {
  bf16x8 r;
  r[0] = (__bf16)u.x; r[1] = (__bf16)u.y; r[2] = (__bf16)u.z; r[3] = (__bf16)u.w;
  r[4] = (__bf16)v.x; r[5] = (__bf16)v.y; r[6] = (__bf16)v.z; r[7] = (__bf16)v.w;
  return r;
}

// ---------------------------------------------------------------------------
// Kernel 2: projections, LDS-staged x via global_load_lds (dest linear,
// both-sides XOR swizzle chunk^=row&15 on global source + ds_read).
// Block = 32 rows, 8 waves, K-step 128, double-buffered 16KB tiles.
// W fragments software-pipelined across ksub (they were latency-exposed).
// Q,K row-major bf16 [B*T][128]; V transposed [B][128][T].
// ---------------------------------------------------------------------------
__global__ __launch_bounds__(512) void proj_kernel(
    const float* __restrict__ x, const __bf16* __restrict__ Wt,
    __bf16* __restrict__ Qb, __bf16* __restrict__ Kb, __bf16* __restrict__ Vt) {
  __shared__ float xs[2][32 * 128];      // 32 KB
  const int tid = threadIdx.x;
  const int wid = tid >> 6;      // 0..7
  const int l   = tid & 63;
  const int c   = l & 15;        // A-row / B-col slot
  const int g   = l >> 4;        // k-group
  const int rbase = blockIdx.x * 32;

  f32x4 acc[3][2];
#pragma unroll
  for (int i = 0; i < 3; ++i) { acc[i][0] = 0.f; acc[i][1] = 0.f; }

  const __bf16* wb[3];
#pragma unroll
  for (int i = 0; i < 3; ++i) {
    int u = wid * 3 + i;
    wb[i] = Wt + ((size_t)(u >> 3) * 128 + (u & 7) * 16 + c) * C_ + g * 8;
  }

  // staging geometry: tile has 32 rows x 32 chunks (16B). Wave w, instr k2,
  // lane l -> dest chunk w*128 + k2*64 + l; row = chunk>>5; p = l&31;
  // source chunk-in-row = p ^ (row&15).
  const int row0 = wid * 4 + (l >> 5);
  const int row1 = row0 + 2;
  const int p_in = l & 31;
  const int src0 = p_in ^ (row0 & 15);
  const int src1 = p_in ^ (row1 & 15);
  const float* gsrc0 = x + (size_t)(rbase + row0) * C_ + src0 * 4;
  const float* gsrc1 = x + (size_t)(rbase + row1) * C_ + src1 * 4;

  auto stage = [&](int t, int buf) {
    __builtin_amdgcn_global_load_lds((gfloat*)(gsrc0 + t * 128),
        (lfloat*)&xs[buf][wid * 512], 16, 0, 0);
    __builtin_amdgcn_global_load_lds((gfloat*)(gsrc1 + t * 128),
        (lfloat*)&xs[buf][wid * 512 + 256], 16, 0, 0);
  };

  stage(0, 0);
  asm volatile("s_waitcnt vmcnt(0)" ::: "memory");
  __syncthreads();

  for (int t = 0; t < 8; ++t) {
    const int cur = t & 1;
    if (t + 1 < 8) stage(t + 1, cur ^ 1);
    const float* xt = &xs[cur][0];
    const int cb = t * 128;
    bf16x8 bfr[3];
#pragma unroll
    for (int i = 0; i < 3; ++i)
      bfr[i] = *reinterpret_cast<const bf16x8*>(wb[i] + cb);
#pragma unroll
    for (int ksub = 0; ksub < 4; ++ksub) {
      bf16x8 bnx[3];
      if (ksub < 3) {
#pragma unroll
        for (int i = 0; i < 3; ++i)
          bnx[i] = *reinterpret_cast<const bf16x8*>(wb[i] + cb + (ksub + 1) * 32);
      }
#pragma unroll
      for (int rt = 0; rt < 2; ++rt) {
        const int rr = rt * 16 + c;          // rr & 15 == c
        const int q  = ksub * 8 + g * 2;     // 16B-chunk index pair (q, q+1)
        float4 lo = *reinterpret_cast<const float4*>(&xt[rr * 128 + ((q ^ c) << 2)]);
        float4 hi = *reinterpret_cast<const float4*>(&xt[rr * 128 + (((q + 1) ^ c) << 2)]);
        bf16x8 a = cvt8p(lo, hi);
#pragma unroll
        for (int i = 0; i < 3; ++i) acc[i][rt] = MFMA(a, bfr[i], acc[i][rt]);
      }
      if (ksub < 3) {
#pragma unroll
        for (int i = 0; i < 3; ++i) bfr[i] = bnx[i];
      }
    }
    asm volatile("s_waitcnt vmcnt(0)" ::: "memory");
    __syncthreads();
  }

#pragma unroll
  for (int i = 0; i < 3; ++i) {
    const int u = wid * 3 + i;
    const int m = u >> 3, nt = u & 7;
    if (m < 2) {
      __bf16* dst = (m == 0) ? Qb : Kb;
#pragma unroll
      for (int rt = 0; rt < 2; ++rt)
#pragma unroll
        for (int rr = 0; rr < 4; ++rr)
          dst[(size_t)(rbase + rt * 16 + 4 * g + rr) * HS_ + nt * 16 + c] =
              (__bf16)acc[i][rt][rr];
    } else {
#pragma unroll
      for (int rt = 0; rt < 2; ++rt) {
        int row = rbase + rt * 16 + 4 * g;
        int bb  = row >> 12;
        int t2  = row & 4095;
        bf16x4 v4;
#pragma unroll
        for (int rr = 0; rr < 4; ++rr) v4[rr] = (__bf16)acc[i][rt][rr];
        *reinterpret_cast<bf16x4*>(Vt + ((size_t)bb * HS_ + nt * 16 + c) * T_ + t2) = v4;
      }
    }
  }
}

// ---------------------------------------------------------------------------
// Kernel 3: causal flash attention. 8 waves/block (R6: 4 waves = 8 waves/CU
// was latency-starved at MfmaUtil 9%); each wave owns the FULL 32 q-rows
// (acc[2][8]) with an 8-way kt split (kt = wid, wid+8, ...) -> 16 waves/CU.
// S^T = mfma(K_perm, Q^T): softmax stats lane-column-local; P per-lane IS
// the PV B-fragment. K next-tile register prefetch; V loads fly under
// softmax VALU. exp2-domain (log2e folded into Wq). 8-wave LDS combine tree.
// b = (bid&7)>>1 gives batch->XCD affinity (K/V working set < 4MB L2/XCD).
// ---------------------------------------------------------------------------
__global__ __launch_bounds__(512, 2) void attn_kernel(
    const __bf16* __restrict__ Qb, const __bf16* __restrict__ Kb,
    const __bf16* __restrict__ Vt, float* __restrict__ out) {
  __shared__ float sm[8][32];
  __shared__ float sl[8][32];
  __shared__ float bufA[32][132];
  __shared__ float bufB[32][132];

  const int tid = threadIdx.x;
  const int wid = tid >> 6;                          // 0..7
  const int l   = tid & 63;
  const int c   = l & 15;
  const int g   = l >> 4;
  const int bid = blockIdx.x;
  const int b   = (bid & 7) >> 1;                    // XCD-affine batch
  const int j   = ((bid >> 3) << 1) | (bid & 1);     // 0..127
  const int qt  = (j < 64) ? (127 - j) : (j - 64);   // big tiles dispatched first
  const int qb  = qt * 32;
  const int kp  = ((l & 12) << 1) | (l & 3);         // A-slot m -> key 8*(m>>2)+(m&3)

  const __bf16* Qp = Qb + (size_t)b * T_ * HS_;
  const __bf16* Kp = Kb + (size_t)b * T_ * HS_;
  const __bf16* Vp = Vt + (size_t)b * HS_ * T_;

  bf16x8 qf[2][4];
#pragma unroll
  for (int rt = 0; rt < 2; ++rt)
#pragma unroll
    for (int cs = 0; cs < 4; ++cs)
      qf[rt][cs] = *reinterpret_cast<const bf16x8*>(
          Qp + (size_t)(qb + rt * 16 + c) * HS_ + cs * 32 + g * 8);

  f32x4 acc[2][8];
#pragma unroll
  for (int i = 0; i < 2; ++i)
#pragma unroll
    for (int d = 0; d < 8; ++d) acc[i][d] = 0.f;
  float mrun[2] = {-INFINITY, -INFINITY};
  float lrun[2] = {0.f, 0.f};

  if (wid <= qt) {
    bf16x8 kreg[8];
    auto kload = [&](int kt) {
      const __bf16* kr = Kp + (size_t)(kt * 32 + kp) * HS_;
#pragma unroll
      for (int cs = 0; cs < 4; ++cs) {
        kreg[2 * cs]     = *reinterpret_cast<const bf16x8*>(kr + cs * 32 + g * 8);
        kreg[2 * cs + 1] = *reinterpret_cast<const bf16x8*>(kr + 4 * HS_ + cs * 32 + g * 8);
      }
    };
    kload(wid);

    for (int kt = wid; kt <= qt; kt += 8) {
      f32x4 s00 = 0.f, s01 = 0.f, s10 = 0.f, s11 = 0.f;
      __builtin_amdgcn_s_setprio(1);
#pragma unroll
      for (int cs = 0; cs < 4; ++cs) {
        s00 = MFMA(kreg[2 * cs], qf[0][cs], s00);
        s01 = MFMA(kreg[2 * cs + 1], qf[0][cs], s01);
        s10 = MFMA(kreg[2 * cs], qf[1][cs], s10);
        s11 = MFMA(kreg[2 * cs + 1], qf[1][cs], s11);
      }
      __builtin_amdgcn_s_setprio(0);

      if (kt + 8 <= qt) kload(kt + 8);        // prefetch next K tile

      bf16x8 vf[8];
      const __bf16* vr = Vp + kt * 32 + g * 8;
#pragma unroll
      for (int db = 0; db < 8; ++db)
        vf[db] = *reinterpret_cast<const bf16x8*>(vr + (size_t)(db * 16 + c) * T_);

      const bool maskt = (kt == qt);           // only the diagonal tile
      bf16x8 pb[2];
#pragma unroll
      for (int rt = 0; rt < 2; ++rt) {
        float p[8];
        const f32x4 sa = rt ? s10 : s00;
        const f32x4 sb = rt ? s11 : s01;
#pragma unroll
        for (int rr = 0; rr < 4; ++rr) { p[rr] = sa[rr]; p[4 + rr] = sb[rr]; }
        if (maskt) {
          const int lim = rt * 16 + c;
#pragma unroll
          for (int jj = 0; jj < 8; ++jj)
            if (8 * g + jj > lim) p[jj] = -INFINITY;
        }
        float t0 = fmaxf(fmaxf(p[0], p[1]), p[2]);
        float t1 = fmaxf(fmaxf(p[3], p[4]), p[5]);
        float t2 = fmaxf(fmaxf(p[6], p[7]), t0);
        float tmax = fmaxf(t1, t2);
        tmax = fmaxf(tmax, __shfl_xor(tmax, 16));
        tmax = fmaxf(tmax, __shfl_xor(tmax, 32));

        if (!__all(tmax <= mrun[rt] + 11.5415603f)) {   // defer-max, log2 units
          float mnew = fmaxf(mrun[rt], tmax);
          float al   = fexp2(mrun[rt] - mnew);
          mrun[rt] = mnew;
          lrun[rt] *= al;
#pragma unroll
          for (int db = 0; db < 8; ++db) acc[rt][db] *= al;
        }
        const float mc = mrun[rt];
#pragma unroll
        for (int jj = 0; jj < 8; ++jj) p[jj] = fexp2(p[jj] - mc);
        float ts = ((p[0] + p[1]) + (p[2] + p[3])) + ((p[4] + p[5]) + (p[6] + p[7]));
        ts += __shfl_xor(ts, 16);
        ts += __shfl_xor(ts, 32);
        lrun[rt] += ts;
#pragma unroll
        for (int jj = 0; jj < 8; ++jj) pb[rt][jj] = (__bf16)p[jj];
      }

      __builtin_amdgcn_s_setprio(1);
#pragma unroll
      for (int db = 0; db < 8; ++db) {
        acc[0][db] = MFMA(vf[db], pb[0], acc[0][db]);
        acc[1][db] = MFMA(vf[db], pb[1], acc[1][db]);
      }
      __builtin_amdgcn_s_setprio(0);
    }
  }

  // ---- combine the 8 waves' partial (m, l, O) ----
  if (g == 0) {
    sm[wid][c] = mrun[0]; sm[wid][16 + c] = mrun[1];
    sl[wid][c] = lrun[0]; sl[wid][16 + c] = lrun[1];
  }
  __syncthreads();

  float linv[2];
#pragma unroll
  for (int rt = 0; rt < 2; ++rt) {
    const int q = rt * 16 + c;
    float ms = sm[0][q];
#pragma unroll
    for (int w = 1; w < 8; ++w) ms = fmaxf(ms, sm[w][q]);
    float ls = 0.f;
#pragma unroll
    for (int w = 0; w < 8; ++w) ls += fexp2(sm[w][q] - ms) * sl[w][q];
    float al = fexp2(mrun[rt] - ms);    // 0 if this wave had no tiles
#pragma unroll
    for (int db = 0; db < 8; ++db) acc[rt][db] *= al;
    linv[rt] = 1.0f / ls;
  }

  auto store_buf = [&](float(*buf)[132]) {
#pragma unroll
    for (int rt = 0; rt < 2; ++rt)
#pragma unroll
      for (int db = 0; db < 8; ++db)
        *reinterpret_cast<f32x4*>(&buf[rt * 16 + c][db * 16 + 4 * g]) = acc[rt][db];
  };
  auto add_buf = [&](float(*buf)[132]) {
#pragma unroll
    for (int rt = 0; rt < 2; ++rt)
#pragma unroll
      for (int db = 0; db < 8; ++db)
        acc[rt][db] += *reinterpret_cast<const f32x4*>(&buf[rt * 16 + c][db * 16 + 4 * g]);
  };

  if (wid == 4) store_buf(bufA);
  if (wid == 5) store_buf(bufB);
  __syncthreads();
  if (wid == 0) add_buf(bufA);          // 0+4
  if (wid == 1) add_buf(bufB);          // 1+5
  __syncthreads();
  if (wid == 6) store_buf(bufA);
  if (wid == 7) store_buf(bufB);
  __syncthreads();
  if (wid == 2) add_buf(bufA);          // 2+6
  if (wid == 3) add_buf(bufB);          // 3+7
  __syncthreads();
  if (wid == 2) store_buf(bufA);
  if (wid == 3) store_buf(bufB);
  __syncthreads();
  if (wid == 0) add_buf(bufA);          // 0+4+2+6
  if (wid == 1) add_buf(bufB);          // 1+5+3+7
  __syncthreads();
  if (wid == 1) store_buf(bufA);
  __syncthreads();

  if (wid == 0) {
    add_buf(bufA);                      // full sum
    float* op = out + ((size_t)b * T_ + qb) * HS_;
#pragma unroll
    for (int rt = 0; rt < 2; ++rt)
#pragma unroll
      for (int db = 0; db < 8; ++db) {
        f32x4 v = acc[rt][db] * linv[rt];
        *reinterpret_cast<f32x4*>(op + (size_t)(rt * 16 + c) * HS_ + db * 16 + 4 * g) = v;
      }
  }
}

// ---------------------------------------------------------------------------
extern "C" void kernel_launch(void* const* d_in, const int* in_sizes, int n_in,
                              void* d_out, int out_size, void* d_ws, size_t ws_size,
                              hipStream_t stream) {
  const float* x  = (const float*)d_in[0];
  const float* Wk = (const float*)d_in[1];
  const float* Wq = (const float*)d_in[2];
  const float* Wv = (const float*)d_in[3];
  float* out = (float*)d_out;

  char* ws = (char*)d_ws;
  __bf16* Wt = (__bf16*)ws;                              // 768 KiB
  __bf16* Qb = (__bf16*)(ws + 786432);                   // 4 MiB
  __bf16* Kb = (__bf16*)(ws + 786432 + 4194304);         // 4 MiB
  __bf16* Vt = (__bf16*)(ws + 786432 + 8388608);         // 4 MiB (transposed V)

  prep_w_kernel<<<48, 256, 0, stream>>>(Wk, Wq, Wv, Wt);
  proj_kernel<<<512, 512, 0, stream>>>(x, Wt, Qb, Kb, Vt);
  attn_kernel<<<512, 512, 0, stream>>>(Qb, Kb, Vt, out);
}

// Round 8
// 125.876 us; speedup vs baseline: 1.1823x; 1.1823x over previous
//
#include <hip/hip_runtime.h>
#include <hip/hip_bf16.h>
#include <math.h>

#define B_  4
#define T_  4096
#define C_  1024
#define HS_ 128

using bf16x8 = __attribute__((ext_vector_type(8))) __bf16;
using bf16x4 = __attribute__((ext_vector_type(4))) __bf16;
using f32x4  = __attribute__((ext_vector_type(4))) float;

#define MFMA(a, b, c) __builtin_amdgcn_mfma_f32_16x16x32_bf16(a, b, c, 0, 0, 0)

typedef __attribute__((address_space(1))) const float gfloat;
typedef __attribute__((address_space(3))) float lfloat;

// fast exp2 via v_exp_f32; trailing s_nop covers the 1-wait-state trans hazard
__device__ inline float fexp2(float x) {
  float r;
  asm volatile("v_exp_f32 %0, %1\n\ts_nop 0" : "=v"(r) : "v"(x));
  return r;
}

// ---------------------------------------------------------------------------
// Kernel 1: W fp32 [1024][128] -> Wt bf16 [3][128][1024] via LDS transpose.
// m=0: Wq scaled by 1/sqrt(128) * log2(e)  (exp2-domain softmax).
// ---------------------------------------------------------------------------
__global__ __launch_bounds__(256) void prep_w_kernel(
    const float* __restrict__ Wk, const float* __restrict__ Wq,
    const float* __restrict__ Wv, __bf16* __restrict__ Wt) {
  const int m  = blockIdx.x >> 4;        // 0..2
  const int k0 = (blockIdx.x & 15) * 64; // k-slab base
  const float* W = (m == 0) ? Wq : ((m == 1) ? Wk : Wv);
  const float scale = (m == 0) ? (0.08838834764831845f * 1.4426950408889634f) : 1.0f;
  __shared__ __bf16 tile[128][72];       // [n][k-within-slab], padded
  const int t = threadIdx.x;
#pragma unroll
  for (int p = 0; p < 8; ++p) {
    int e  = p * 1024 + t * 4;
    int r  = e >> 7;                     // 0..63
    int cc = e & 127;
    float4 w = *reinterpret_cast<const float4*>(&W[(size_t)(k0 + r) * HS_ + cc]);
    tile[cc + 0][r] = (__bf16)(w.x * scale);
    tile[cc + 1][r] = (__bf16)(w.y * scale);
    tile[cc + 2][r] = (__bf16)(w.z * scale);
    tile[cc + 3][r] = (__bf16)(w.w * scale);
  }
  __syncthreads();
#pragma unroll
  for (int p = 0; p < 4; ++p) {
    int e  = p * 2048 + t * 8;
    int n  = e >> 6;                     // 0..127
    int kk = e & 63;
    bf16x8 v;
#pragma unroll
    for (int jj = 0; jj < 8; ++jj) v[jj] = tile[n][kk + jj];
    *reinterpret_cast<bf16x8*>(&Wt[((size_t)m * 128 + n) * C_ + k0 + kk]) = v;
  }
}

__device__ inline bf16x8 cvt8p(float4 u, float4 v) {
  bf16x8 r;
  r[0] = (__bf16)u.x; r[1] = (__bf16)u.y; r[2] = (__bf16)u.z; r[3] = (__bf16)u.w;
  r[4] = (__bf16)v.x; r[5] = (__bf16)v.y; r[6] = (__bf16)v.z; r[7] = (__bf16)v.w;
  return r;
}

// ---------------------------------------------------------------------------
// Kernel 2: projections, LDS-staged x via global_load_lds (linear dest,
// both-sides XOR swizzle chunk^=row&15; measured 0 bank conflicts R5/R6).
// R7 change: 4 waves x 6 (m,nt) units (was 8x3) -> each A-frag ds_read_b128
// pair feeds 6 MFMAs instead of 3 (proj was LDS-read-throughput bound at
// MfmaUtil 4.4%). Block = 32 rows, K-step 128, double-buffered 16KB tiles.
// Q,K row-major bf16 [B*T][128]; V transposed [B][128][T].
// ---------------------------------------------------------------------------
__global__ __launch_bounds__(256) void proj_kernel(
    const float* __restrict__ x, const __bf16* __restrict__ Wt,
    __bf16* __restrict__ Qb, __bf16* __restrict__ Kb, __bf16* __restrict__ Vt) {
  __shared__ float xs[2][32 * 128];      // 32 KB
  const int tid = threadIdx.x;
  const int wid = tid >> 6;      // 0..3
  const int l   = tid & 63;
  const int c   = l & 15;        // A-row / B-col slot
  const int g   = l >> 4;        // k-group
  const int rbase = blockIdx.x * 32;

  f32x4 acc[6][2];
#pragma unroll
  for (int i = 0; i < 6; ++i) { acc[i][0] = 0.f; acc[i][1] = 0.f; }

  const __bf16* wb[6];
#pragma unroll
  for (int i = 0; i < 6; ++i) {
    int u = wid * 6 + i;
    wb[i] = Wt + ((size_t)(u >> 3) * 128 + (u & 7) * 16 + c) * C_ + g * 8;
  }

  // staging: tile 32 rows x 32 chunks(16B). wave w instr k2 lane l ->
  // dest chunk w*256+k2*64+l (linear); row = w*8+k2*2+(l>>5); p=l&31;
  // source chunk-in-row = p ^ (row&15) (same involution applied on read).
  const int row00 = wid * 8 + (l >> 5);
  const int p_in  = l & 31;
  const float* gs[4];
#pragma unroll
  for (int k2 = 0; k2 < 4; ++k2) {
    int row = row00 + 2 * k2;
    gs[k2] = x + (size_t)(rbase + row) * C_ + (p_in ^ (row & 15)) * 4;
  }

  auto stage = [&](int t, int buf) {
#pragma unroll
    for (int k2 = 0; k2 < 4; ++k2)
      __builtin_amdgcn_global_load_lds((gfloat*)(gs[k2] + t * 128),
          (lfloat*)&xs[buf][wid * 1024 + k2 * 256], 16, 0, 0);
  };

  stage(0, 0);
  asm volatile("s_waitcnt vmcnt(0)" ::: "memory");
  __syncthreads();

  for (int t = 0; t < 8; ++t) {
    const int cur = t & 1;
    if (t + 1 < 8) stage(t + 1, cur ^ 1);
    const float* xt = &xs[cur][0];
    const int cb = t * 128;
    bf16x8 bfr[6];
#pragma unroll
    for (int i = 0; i < 6; ++i)
      bfr[i] = *reinterpret_cast<const bf16x8*>(wb[i] + cb);
#pragma unroll
    for (int ksub = 0; ksub < 4; ++ksub) {
      bf16x8 bnx[6];
      if (ksub < 3) {
#pragma unroll
        for (int i = 0; i < 6; ++i)
          bnx[i] = *reinterpret_cast<const bf16x8*>(wb[i] + cb + (ksub + 1) * 32);
      }
#pragma unroll
      for (int rt = 0; rt < 2; ++rt) {
        const int rr = rt * 16 + c;          // rr & 15 == c
        const int q  = ksub * 8 + g * 2;     // 16B-chunk index pair (q, q+1)
        float4 lo = *reinterpret_cast<const float4*>(&xt[rr * 128 + ((q ^ c) << 2)]);
        float4 hi = *reinterpret_cast<const float4*>(&xt[rr * 128 + (((q + 1) ^ c) << 2)]);
        bf16x8 a = cvt8p(lo, hi);
#pragma unroll
        for (int i = 0; i < 6; ++i) acc[i][rt] = MFMA(a, bfr[i], acc[i][rt]);
      }
      if (ksub < 3) {
#pragma unroll
        for (int i = 0; i < 6; ++i) bfr[i] = bnx[i];
      }
    }
    asm volatile("s_waitcnt vmcnt(0)" ::: "memory");
    __syncthreads();
  }

#pragma unroll
  for (int i = 0; i < 6; ++i) {
    const int u = wid * 6 + i;
    const int m = u >> 3, nt = u & 7;
    if (m < 2) {
      __bf16* dst = (m == 0) ? Qb : Kb;
#pragma unroll
      for (int rt = 0; rt < 2; ++rt)
#pragma unroll
        for (int rr = 0; rr < 4; ++rr)
          dst[(size_t)(rbase + rt * 16 + 4 * g + rr) * HS_ + nt * 16 + c] =
              (__bf16)acc[i][rt][rr];
    } else {
#pragma unroll
      for (int rt = 0; rt < 2; ++rt) {
        int row = rbase + rt * 16 + 4 * g;
        int bb  = row >> 12;
        int t2  = row & 4095;
        bf16x4 v4;
#pragma unroll
        for (int rr = 0; rr < 4; ++rr) v4[rr] = (__bf16)acc[i][rt][rr];
        *reinterpret_cast<bf16x4*>(Vt + ((size_t)bb * HS_ + nt * 16 + c) * T_ + t2) = v4;
      }
    }
  }
}

// ---------------------------------------------------------------------------
// Kernel 3: causal flash attention. Back to R6's 4-wave/256-thr blocks (R7's
// 8-wave blocks broke 2-blocks/CU co-residency -> heavy/light serialization).
// R7 change: softmax OFF the critical path — no per-tile cross-lane traffic:
//  * per-lane 8-max + __all() gate (scalar); full cross-lane max only in the
//    rare rescale branch,
//  * lrun kept as per-lane partial, reduced by 2 shuffles ONCE at wave end
//    (rescales are column-uniform so partial sums stay consistent),
//  * V loads issued before K-prefetch so PV's vmcnt leaves K in flight.
// S^T = mfma(K_perm, Q^T); P per-lane IS the PV B-fragment. exp2 domain.
// ---------------------------------------------------------------------------
__global__ __launch_bounds__(256, 2) void attn_kernel(
    const __bf16* __restrict__ Qb, const __bf16* __restrict__ Kb,
    const __bf16* __restrict__ Vt, float* __restrict__ out) {
  __shared__ float sm[4][32];
  __shared__ float sl[4][32];
  __shared__ float bufA[32][132];
  __shared__ float bufB[32][132];

  const int tid = threadIdx.x;
  const int wid = tid >> 6;
  const int l   = tid & 63;
  const int c   = l & 15;
  const int g   = l >> 4;
  const int bid = blockIdx.x;
  const int b   = (bid & 7) >> 1;                    // XCD-affine batch
  const int j   = ((bid >> 3) << 1) | (bid & 1);     // 0..127
  const int qt  = (j < 64) ? (127 - j) : (j - 64);   // big tiles dispatched first
  const int qb  = qt * 32;
  const int kp  = ((l & 12) << 1) | (l & 3);         // A-slot m -> key 8*(m>>2)+(m&3)

  const __bf16* Qp = Qb + (size_t)b * T_ * HS_;
  const __bf16* Kp = Kb + (size_t)b * T_ * HS_;
  const __bf16* Vp = Vt + (size_t)b * HS_ * T_;

  bf16x8 qf[2][4];
#pragma unroll
  for (int rt = 0; rt < 2; ++rt)
#pragma unroll
    for (int cs = 0; cs < 4; ++cs)
      qf[rt][cs] = *reinterpret_cast<const bf16x8*>(
          Qp + (size_t)(qb + rt * 16 + c) * HS_ + cs * 32 + g * 8);

  f32x4 acc[2][8];
#pragma unroll
  for (int i = 0; i < 2; ++i)
#pragma unroll
    for (int d = 0; d < 8; ++d) acc[i][d] = 0.f;
  float mrun[2] = {-INFINITY, -INFINITY};
  float lrun[2] = {0.f, 0.f};   // PER-LANE partial sums (reduced at wave end)

  if (wid <= qt) {
    bf16x8 kreg[8];
    auto kload = [&](int kt) {
      const __bf16* kr = Kp + (size_t)(kt * 32 + kp) * HS_;
#pragma unroll
      for (int cs = 0; cs < 4; ++cs) {
        kreg[2 * cs]     = *reinterpret_cast<const bf16x8*>(kr + cs * 32 + g * 8);
        kreg[2 * cs + 1] = *reinterpret_cast<const bf16x8*>(kr + 4 * HS_ + cs * 32 + g * 8);
      }
    };
    kload(wid);

    for (int kt = wid; kt <= qt; kt += 4) {
      f32x4 s00 = 0.f, s01 = 0.f, s10 = 0.f, s11 = 0.f;
      __builtin_amdgcn_s_setprio(1);
#pragma unroll
      for (int cs = 0; cs < 4; ++cs) {
        s00 = MFMA(kreg[2 * cs], qf[0][cs], s00);
        s01 = MFMA(kreg[2 * cs + 1], qf[0][cs], s01);
        s10 = MFMA(kreg[2 * cs], qf[1][cs], s10);
        s11 = MFMA(kreg[2 * cs + 1], qf[1][cs], s11);
      }
      __builtin_amdgcn_s_setprio(0);

      bf16x8 vf[8];
      const __bf16* vr = Vp + kt * 32 + g * 8;
#pragma unroll
      for (int db = 0; db < 8; ++db)
        vf[db] = *reinterpret_cast<const bf16x8*>(vr + (size_t)(db * 16 + c) * T_);

      if (kt + 4 <= qt) kload(kt + 4);        // prefetch next K tile

      const bool maskt = (kt == qt);           // only the diagonal tile
      bf16x8 pb[2];
#pragma unroll
      for (int rt = 0; rt < 2; ++rt) {
        float p[8];
        const f32x4 sa = rt ? s10 : s00;
        const f32x4 sb = rt ? s11 : s01;
#pragma unroll
        for (int rr = 0; rr < 4; ++rr) { p[rr] = sa[rr]; p[4 + rr] = sb[rr]; }
        if (maskt) {
          const int lim = rt * 16 + c;
#pragma unroll
          for (int jj = 0; jj < 8; ++jj)
            if (8 * g + jj > lim) p[jj] = -INFINITY;
        }
        // per-lane max only (no cross-lane on the common path)
        float t0 = fmaxf(fmaxf(p[0], p[1]), p[2]);
        float t1 = fmaxf(fmaxf(p[3], p[4]), p[5]);
        float t2 = fmaxf(fmaxf(p[6], p[7]), t0);
        float tmax = fmaxf(t1, t2);

        if (!__all(tmax <= mrun[rt] + 11.5415603f)) {   // rare: defer-max fired
          float cmax = fmaxf(tmax, __shfl_xor(tmax, 16));
          cmax = fmaxf(cmax, __shfl_xor(cmax, 32));     // column max (over g)
          float mnew = fmaxf(mrun[rt], cmax);
          float al   = fexp2(mrun[rt] - mnew);
          mrun[rt] = mnew;
          lrun[rt] *= al;
#pragma unroll
          for (int db = 0; db < 8; ++db) acc[rt][db] *= al;
        }
        const float mc = mrun[rt];
#pragma unroll
        for (int jj = 0; jj < 8; ++jj) p[jj] = fexp2(p[jj] - mc);
        lrun[rt] += ((p[0] + p[1]) + (p[2] + p[3])) + ((p[4] + p[5]) + (p[6] + p[7]));
#pragma unroll
        for (int jj = 0; jj < 8; ++jj) pb[rt][jj] = (__bf16)p[jj];
      }

      __builtin_amdgcn_s_setprio(1);
#pragma unroll
      for (int db = 0; db < 8; ++db) {
        acc[0][db] = MFMA(vf[db], pb[0], acc[0][db]);
        acc[1][db] = MFMA(vf[db], pb[1], acc[1][db]);
      }
      __builtin_amdgcn_s_setprio(0);
    }
  }

  // wave-end: reduce per-lane l partials across the 4 g-lanes of each column
#pragma unroll
  for (int rt = 0; rt < 2; ++rt) {
    lrun[rt] += __shfl_xor(lrun[rt], 16);
    lrun[rt] += __shfl_xor(lrun[rt], 32);
  }

  // ---- combine the 4 waves' partial (m, l, O) ----
  if (g == 0) {
    sm[wid][c] = mrun[0]; sm[wid][16 + c] = mrun[1];
    sl[wid][c] = lrun[0]; sl[wid][16 + c] = lrun[1];
  }
  __syncthreads();

  float linv[2];
#pragma unroll
  for (int rt = 0; rt < 2; ++rt) {
    const int q = rt * 16 + c;
    float ms = fmaxf(fmaxf(sm[0][q], sm[1][q]), fmaxf(sm[2][q], sm[3][q]));
    float ls = fexp2(sm[0][q] - ms) * sl[0][q] + fexp2(sm[1][q] - ms) * sl[1][q]
             + fexp2(sm[2][q] - ms) * sl[2][q] + fexp2(sm[3][q] - ms) * sl[3][q];
    float al = fexp2(mrun[rt] - ms);
#pragma unroll
    for (int db = 0; db < 8; ++db) acc[rt][db] *= al;
    linv[rt] = 1.0f / ls;
  }

  auto store_buf = [&](float(*buf)[132]) {
#pragma unroll
    for (int rt = 0; rt < 2; ++rt)
#pragma unroll
      for (int db = 0; db < 8; ++db)
        *reinterpret_cast<f32x4*>(&buf[rt * 16 + c][db * 16 + 4 * g]) = acc[rt][db];
  };
  auto add_buf = [&](float(*buf)[132]) {
#pragma unroll
    for (int rt = 0; rt < 2; ++rt)
#pragma unroll
      for (int db = 0; db < 8; ++db)
        acc[rt][db] += *reinterpret_cast<const f32x4*>(&buf[rt * 16 + c][db * 16 + 4 * g]);
  };

  if (wid == 2) store_buf(bufA);
  if (wid == 3) store_buf(bufB);
  __syncthreads();
  if (wid == 0) add_buf(bufA);
  if (wid == 1) add_buf(bufB);
  __syncthreads();
  if (wid == 1) store_buf(bufA);
  __syncthreads();
  if (wid == 0) {
    add_buf(bufA);
    float* op = out + ((size_t)b * T_ + qb) * HS_;
#pragma unroll
    for (int rt = 0; rt < 2; ++rt)
#pragma unroll
      for (int db = 0; db < 8; ++db) {
        f32x4 v = acc[rt][db] * linv[rt];
        *reinterpret_cast<f32x4*>(op + (size_t)(rt * 16 + c) * HS_ + db * 16 + 4 * g) = v;
      }
  }
}

// ---------------------------------------------------------------------------
extern "C" void kernel_launch(void* const* d_in, const int* in_sizes, int n_in,
                              void* d_out, int out_size, void* d_ws, size_t ws_size,
                              hipStream_t stream) {
  const float* x  = (const float*)d_in[0];
  const float* Wk = (const float*)d_in[1];
  const float* Wq = (const float*)d_in[2];
  const float* Wv = (const float*)d_in[3];
  float* out = (float*)d_out;

  char* ws = (char*)d_ws;
  __bf16* Wt = (__bf16*)ws;                              // 768 KiB
  __bf16* Qb = (__bf16*)(ws + 786432);                   // 4 MiB
  __bf16* Kb = (__bf16*)(ws + 786432 + 4194304);         // 4 MiB
  __bf16* Vt = (__bf16*)(ws + 786432 + 8388608);         // 4 MiB (transposed V)

  prep_w_kernel<<<48, 256, 0, stream>>>(Wk, Wq, Wv, Wt);
  proj_kernel<<<512, 256, 0, stream>>>(x, Wt, Qb, Kb, Vt);
  attn_kernel<<<512, 256, 0, stream>>>(Qb, Kb, Vt, out);
}

// Round 9
// 88.990 us; speedup vs baseline: 1.6724x; 1.4145x over previous
//
#include <hip/hip_runtime.h>
#include <hip/hip_bf16.h>
#include <math.h>

#define B_  4
#define T_  4096
#define C_  1024
#define HS_ 128

using bf16x8 = __attribute__((ext_vector_type(8))) __bf16;
using bf16x4 = __attribute__((ext_vector_type(4))) __bf16;
using f32x4  = __attribute__((ext_vector_type(4))) float;

#define MFMA(a, b, c) __builtin_amdgcn_mfma_f32_16x16x32_bf16(a, b, c, 0, 0, 0)

typedef __attribute__((address_space(1))) const float gfloat;
typedef __attribute__((address_space(3))) float lfloat;

// fast exp2 via v_exp_f32; trailing s_nop covers the 1-wait-state trans hazard
__device__ inline float fexp2(float x) {
  float r;
  asm volatile("v_exp_f32 %0, %1\n\ts_nop 0" : "=v"(r) : "v"(x));
  return r;
}

// ---------------------------------------------------------------------------
// Fragment-tiled layouts (R8 post-mortem: attn loads were 32-64 cache-line
// gathers per instruction -> ~16x L1/L2 request amplification, the real 10x
// gap between MFMA time and wall time). Per 32-row tile, store data in the
// exact [chunk][lane][8 bf16] order attn's MFMA fragments consume:
//   Qf[b*128+t][j=rt*4+cs][l][e] = Q[t*32 + rt*16 + (l&15)][cs*32+(l>>4)*8+e]
//   Kf[b*128+t][j=2cs+hi ][l][e] = K[t*32 + kp(l&15)+4hi   ][cs*32+(l>>4)*8+e]
//   Vf[b*128+t][j=db     ][l][e] = V[t*32 + (l>>4)*8+e     ][db*16 + (l&15)]
// (kp(c)=((c&12)<<1)|(c&3)).  Every attn load: base + j*512 + l*8 -> 64
// lanes x 16B = one contiguous 1KB block. Verified element-wise (R9 notes).
// ---------------------------------------------------------------------------

// ---------------------------------------------------------------------------
// Kernel 1: W fp32 [1024][128] -> Wt bf16 [3][128][1024] via LDS transpose.
// m=0: Wq scaled by 1/sqrt(128) * log2(e)  (exp2-domain softmax).
// ---------------------------------------------------------------------------
__global__ __launch_bounds__(256) void prep_w_kernel(
    const float* __restrict__ Wk, const float* __restrict__ Wq,
    const float* __restrict__ Wv, __bf16* __restrict__ Wt) {
  const int m  = blockIdx.x >> 4;        // 0..2
  const int k0 = (blockIdx.x & 15) * 64; // k-slab base
  const float* W = (m == 0) ? Wq : ((m == 1) ? Wk : Wv);
  const float scale = (m == 0) ? (0.08838834764831845f * 1.4426950408889634f) : 1.0f;
  __shared__ __bf16 tile[128][72];       // [n][k-within-slab], padded
  const int t = threadIdx.x;
#pragma unroll
  for (int p = 0; p < 8; ++p) {
    int e  = p * 1024 + t * 4;
    int r  = e >> 7;                     // 0..63
    int cc = e & 127;
    float4 w = *reinterpret_cast<const float4*>(&W[(size_t)(k0 + r) * HS_ + cc]);
    tile[cc + 0][r] = (__bf16)(w.x * scale);
    tile[cc + 1][r] = (__bf16)(w.y * scale);
    tile[cc + 2][r] = (__bf16)(w.z * scale);
    tile[cc + 3][r] = (__bf16)(w.w * scale);
  }
  __syncthreads();
#pragma unroll
  for (int p = 0; p < 4; ++p) {
    int e  = p * 2048 + t * 8;
    int n  = e >> 6;                     // 0..127
    int kk = e & 63;
    bf16x8 v;
#pragma unroll
    for (int jj = 0; jj < 8; ++jj) v[jj] = tile[n][kk + jj];
    *reinterpret_cast<bf16x8*>(&Wt[((size_t)m * 128 + n) * C_ + k0 + kk]) = v;
  }
}

__device__ inline bf16x8 cvt8p(float4 u, float4 v) {
  bf16x8 r;
  r[0] = (__bf16)u.x; r[1] = (__bf16)u.y; r[2] = (__bf16)u.z; r[3] = (__bf16)u.w;
  r[4] = (__bf16)v.x; r[5] = (__bf16)v.y; r[6] = (__bf16)v.z; r[7] = (__bf16)v.w;
  return r;
}

// ---------------------------------------------------------------------------
// Kernel 2: projections, LDS-staged x via global_load_lds (linear dest,
// both-sides XOR swizzle chunk^=row&15; measured 0 bank conflicts R5-R8).
// Block = 32 rows (= exactly one fragment tile), 4 waves x 6 (m,nt) units,
// K-step 128, double-buffered 16KB x-tiles, W next-ksub reg prefetch.
// Epilogue writes Q/K/V in the fragment-tiled layouts above (same store
// count as before; V scatter actually improves from 64-line to 4-line).
// ---------------------------------------------------------------------------
__global__ __launch_bounds__(256) void proj_kernel(
    const float* __restrict__ x, const __bf16* __restrict__ Wt,
    __bf16* __restrict__ Qf, __bf16* __restrict__ Kf, __bf16* __restrict__ Vf) {
  __shared__ float xs[2][32 * 128];      // 32 KB
  const int tid = threadIdx.x;
  const int wid = tid >> 6;      // 0..3
  const int l   = tid & 63;
  const int c   = l & 15;        // A-row / B-col slot
  const int g   = l >> 4;        // k-group
  const int rbase = blockIdx.x * 32;
  const size_t tile = blockIdx.x;          // global tile = b*128 + (t>>5)

  f32x4 acc[6][2];
#pragma unroll
  for (int i = 0; i < 6; ++i) { acc[i][0] = 0.f; acc[i][1] = 0.f; }

  const __bf16* wb[6];
#pragma unroll
  for (int i = 0; i < 6; ++i) {
    int u = wid * 6 + i;
    wb[i] = Wt + ((size_t)(u >> 3) * 128 + (u & 7) * 16 + c) * C_ + g * 8;
  }

  // staging: tile 32 rows x 32 chunks(16B). wave w instr k2 lane l ->
  // dest chunk w*256+k2*64+l (linear); row = w*8+k2*2+(l>>5); p=l&31;
  // source chunk-in-row = p ^ (row&15) (same involution applied on read).
  const int row00 = wid * 8 + (l >> 5);
  const int p_in  = l & 31;
  const float* gs[4];
#pragma unroll
  for (int k2 = 0; k2 < 4; ++k2) {
    int row = row00 + 2 * k2;
    gs[k2] = x + (size_t)(rbase + row) * C_ + (p_in ^ (row & 15)) * 4;
  }

  auto stage = [&](int t, int buf) {
#pragma unroll
    for (int k2 = 0; k2 < 4; ++k2)
      __builtin_amdgcn_global_load_lds((gfloat*)(gs[k2] + t * 128),
          (lfloat*)&xs[buf][wid * 1024 + k2 * 256], 16, 0, 0);
  };

  stage(0, 0);
  asm volatile("s_waitcnt vmcnt(0)" ::: "memory");
  __syncthreads();

  for (int t = 0; t < 8; ++t) {
    const int cur = t & 1;
    if (t + 1 < 8) stage(t + 1, cur ^ 1);
    const float* xt = &xs[cur][0];
    const int cb = t * 128;
    bf16x8 bfr[6];
#pragma unroll
    for (int i = 0; i < 6; ++i)
      bfr[i] = *reinterpret_cast<const bf16x8*>(wb[i] + cb);
#pragma unroll
    for (int ksub = 0; ksub < 4; ++ksub) {
      bf16x8 bnx[6];
      if (ksub < 3) {
#pragma unroll
        for (int i = 0; i < 6; ++i)
          bnx[i] = *reinterpret_cast<const bf16x8*>(wb[i] + cb + (ksub + 1) * 32);
      }
#pragma unroll
      for (int rt = 0; rt < 2; ++rt) {
        const int rr = rt * 16 + c;          // rr & 15 == c
        const int q  = ksub * 8 + g * 2;     // 16B-chunk index pair (q, q+1)
        float4 lo = *reinterpret_cast<const float4*>(&xt[rr * 128 + ((q ^ c) << 2)]);
        float4 hi = *reinterpret_cast<const float4*>(&xt[rr * 128 + (((q + 1) ^ c) << 2)]);
        bf16x8 a = cvt8p(lo, hi);
#pragma unroll
        for (int i = 0; i < 6; ++i) acc[i][rt] = MFMA(a, bfr[i], acc[i][rt]);
      }
      if (ksub < 3) {
#pragma unroll
        for (int i = 0; i < 6; ++i) bfr[i] = bnx[i];
      }
    }
    asm volatile("s_waitcnt vmcnt(0)" ::: "memory");
    __syncthreads();
  }

  // ---- epilogue: fragment-tiled stores ----
  // Producer element: X[row = rt*16+4g+rr][col = nt*16+c], lane invariants:
  const int gq = ((0x0) | 0); (void)gq;
#pragma unroll
  for (int i = 0; i < 6; ++i) {
    const int u = wid * 6 + i;
    const int m = u >> 3, nt = u & 7;
    const int gprime = ((nt & 1) << 1) + (c >> 3);  // col-group (l'>>4)
    const int e = c & 7;
    if (m == 0) {
      // j = rt*4 + (nt>>1); l' = gprime*16 + (4g+rr)
#pragma unroll
      for (int rt = 0; rt < 2; ++rt)
#pragma unroll
        for (int rr = 0; rr < 4; ++rr)
          Qf[(tile * 8 + rt * 4 + (nt >> 1)) * 512 +
             (gprime * 16 + 4 * g + rr) * 8 + e] = (__bf16)acc[i][rt][rr];
    } else if (m == 1) {
      // rho = rt*16+4g+rr: hi = g&1; c'' = ((2rt+(g>>1))<<2)|rr
#pragma unroll
      for (int rt = 0; rt < 2; ++rt)
#pragma unroll
        for (int rr = 0; rr < 4; ++rr)
          Kf[(tile * 8 + 2 * (nt >> 1) + (g & 1)) * 512 +
             (gprime * 16 + (((2 * rt + (g >> 1)) << 2) | rr)) * 8 + e] =
              (__bf16)acc[i][rt][rr];
    } else {
      // j = nt; l' = (2rt+(g>>1))*16 + c; e = 4(g&1)+rr (contiguous in rr)
#pragma unroll
      for (int rt = 0; rt < 2; ++rt) {
        bf16x4 v4;
#pragma unroll
        for (int rr = 0; rr < 4; ++rr) v4[rr] = (__bf16)acc[i][rt][rr];
        *reinterpret_cast<bf16x4*>(
            Vf + (tile * 8 + nt) * 512 +
            ((2 * rt + (g >> 1)) * 16 + c) * 8 + 4 * (g & 1)) = v4;
      }
    }
  }
}

// ---------------------------------------------------------------------------
// Kernel 3: causal flash attention. 4 waves/block; each wave owns the FULL
// 32 q-rows (acc[2][8]) with 4-way kt split. All Q/K/V global loads are now
// fragment-tiled: base + chunk*512 + l*8 -> perfectly coalesced 1KB blocks
// (was 32-64 cache lines per instruction -> the R6-R8 latency wall).
// S^T = mfma(K_perm, Q^T); P per-lane IS the PV B-fragment. Per-lane softmax
// gate (__all), lrun per-lane partial reduced once at wave end. exp2 domain.
// ---------------------------------------------------------------------------
__global__ __launch_bounds__(256, 2) void attn_kernel(
    const __bf16* __restrict__ Qf, const __bf16* __restrict__ Kf,
    const __bf16* __restrict__ Vf, float* __restrict__ out) {
  __shared__ float sm[4][32];
  __shared__ float sl[4][32];
  __shared__ float bufA[32][132];
  __shared__ float bufB[32][132];

  const int tid = threadIdx.x;
  const int wid = tid >> 6;
  const int l   = tid & 63;
  const int c   = l & 15;
  const int g   = l >> 4;
  const int bid = blockIdx.x;
  const int b   = (bid & 7) >> 1;                    // XCD-affine batch
  const int j   = ((bid >> 3) << 1) | (bid & 1);     // 0..127
  const int qt  = (j < 64) ? (127 - j) : (j - 64);   // big tiles dispatched first
  const int qb  = qt * 32;

  bf16x8 qf[2][4];
  {
    const __bf16* Qt = Qf + (size_t)(b * 128 + qt) * 4096 + l * 8;
#pragma unroll
    for (int rt = 0; rt < 2; ++rt)
#pragma unroll
      for (int cs = 0; cs < 4; ++cs)
        qf[rt][cs] = *reinterpret_cast<const bf16x8*>(Qt + (rt * 4 + cs) * 512);
  }

  f32x4 acc[2][8];
#pragma unroll
  for (int i = 0; i < 2; ++i)
#pragma unroll
    for (int d = 0; d < 8; ++d) acc[i][d] = 0.f;
  float mrun[2] = {-INFINITY, -INFINITY};
  float lrun[2] = {0.f, 0.f};   // PER-LANE partial sums (reduced at wave end)

  if (wid <= qt) {
    const __bf16* Kb8 = Kf + (size_t)b * 128 * 4096 + l * 8;
    const __bf16* Vb8 = Vf + (size_t)b * 128 * 4096 + l * 8;
    bf16x8 kreg[8];
    auto kload = [&](int kt) {
      const __bf16* kb = Kb8 + (size_t)kt * 4096;
#pragma unroll
      for (int jj = 0; jj < 8; ++jj)
        kreg[jj] = *reinterpret_cast<const bf16x8*>(kb + jj * 512);
    };
    kload(wid);

    for (int kt = wid; kt <= qt; kt += 4) {
      f32x4 s00 = 0.f, s01 = 0.f, s10 = 0.f, s11 = 0.f;
      __builtin_amdgcn_s_setprio(1);
#pragma unroll
      for (int cs = 0; cs < 4; ++cs) {
        s00 = MFMA(kreg[2 * cs], qf[0][cs], s00);
        s01 = MFMA(kreg[2 * cs + 1], qf[0][cs], s01);
        s10 = MFMA(kreg[2 * cs], qf[1][cs], s10);
        s11 = MFMA(kreg[2 * cs + 1], qf[1][cs], s11);
      }
      __builtin_amdgcn_s_setprio(0);

      bf16x8 vf[8];
      {
        const __bf16* vb = Vb8 + (size_t)kt * 4096;
#pragma unroll
        for (int db = 0; db < 8; ++db)
          vf[db] = *reinterpret_cast<const bf16x8*>(vb + db * 512);
      }

      if (kt + 4 <= qt) kload(kt + 4);        // prefetch next K tile

      const bool maskt = (kt == qt);           // only the diagonal tile
      bf16x8 pb[2];
#pragma unroll
      for (int rt = 0; rt < 2; ++rt) {
        float p[8];
        const f32x4 sa = rt ? s10 : s00;
        const f32x4 sb = rt ? s11 : s01;
#pragma unroll
        for (int rr = 0; rr < 4; ++rr) { p[rr] = sa[rr]; p[4 + rr] = sb[rr]; }
        if (maskt) {
          const int lim = rt * 16 + c;
#pragma unroll
          for (int jj = 0; jj < 8; ++jj)
            if (8 * g + jj > lim) p[jj] = -INFINITY;
        }
        // per-lane max only (no cross-lane on the common path)
        float t0 = fmaxf(fmaxf(p[0], p[1]), p[2]);
        float t1 = fmaxf(fmaxf(p[3], p[4]), p[5]);
        float t2 = fmaxf(fmaxf(p[6], p[7]), t0);
        float tmax = fmaxf(t1, t2);

        if (!__all(tmax <= mrun[rt] + 11.5415603f)) {   // rare: defer-max fired
          float cmax = fmaxf(tmax, __shfl_xor(tmax, 16));
          cmax = fmaxf(cmax, __shfl_xor(cmax, 32));     // column max (over g)
          float mnew = fmaxf(mrun[rt], cmax);
          float al   = fexp2(mrun[rt] - mnew);
          mrun[rt] = mnew;
          lrun[rt] *= al;
#pragma unroll
          for (int db = 0; db < 8; ++db) acc[rt][db] *= al;
        }
        const float mc = mrun[rt];
#pragma unroll
        for (int jj = 0; jj < 8; ++jj) p[jj] = fexp2(p[jj] - mc);
        lrun[rt] += ((p[0] + p[1]) + (p[2] + p[3])) + ((p[4] + p[5]) + (p[6] + p[7]));
#pragma unroll
        for (int jj = 0; jj < 8; ++jj) pb[rt][jj] = (__bf16)p[jj];
      }

      __builtin_amdgcn_s_setprio(1);
#pragma unroll
      for (int db = 0; db < 8; ++db) {
        acc[0][db] = MFMA(vf[db], pb[0], acc[0][db]);
        acc[1][db] = MFMA(vf[db], pb[1], acc[1][db]);
      }
      __builtin_amdgcn_s_setprio(0);
    }
  }

  // wave-end: reduce per-lane l partials across the 4 g-lanes of each column
#pragma unroll
  for (int rt = 0; rt < 2; ++rt) {
    lrun[rt] += __shfl_xor(lrun[rt], 16);
    lrun[rt] += __shfl_xor(lrun[rt], 32);
  }

  // ---- combine the 4 waves' partial (m, l, O) ----
  if (g == 0) {
    sm[wid][c] = mrun[0]; sm[wid][16 + c] = mrun[1];
    sl[wid][c] = lrun[0]; sl[wid][16 + c] = lrun[1];
  }
  __syncthreads();

  float linv[2];
#pragma unroll
  for (int rt = 0; rt < 2; ++rt) {
    const int q = rt * 16 + c;
    float ms = fmaxf(fmaxf(sm[0][q], sm[1][q]), fmaxf(sm[2][q], sm[3][q]));
    float ls = fexp2(sm[0][q] - ms) * sl[0][q] + fexp2(sm[1][q] - ms) * sl[1][q]
             + fexp2(sm[2][q] - ms) * sl[2][q] + fexp2(sm[3][q] - ms) * sl[3][q];
    float al = fexp2(mrun[rt] - ms);
#pragma unroll
    for (int db = 0; db < 8; ++db) acc[rt][db] *= al;
    linv[rt] = 1.0f / ls;
  }

  auto store_buf = [&](float(*buf)[132]) {
#pragma unroll
    for (int rt = 0; rt < 2; ++rt)
#pragma unroll
      for (int db = 0; db < 8; ++db)
        *reinterpret_cast<f32x4*>(&buf[rt * 16 + c][db * 16 + 4 * g]) = acc[rt][db];
  };
  auto add_buf = [&](float(*buf)[132]) {
#pragma unroll
    for (int rt = 0; rt < 2; ++rt)
#pragma unroll
      for (int db = 0; db < 8; ++db)
        acc[rt][db] += *reinterpret_cast<const f32x4*>(&buf[rt * 16 + c][db * 16 + 4 * g]);
  };

  if (wid == 2) store_buf(bufA);
  if (wid == 3) store_buf(bufB);
  __syncthreads();
  if (wid == 0) add_buf(bufA);
  if (wid == 1) add_buf(bufB);
  __syncthreads();
  if (wid == 1) store_buf(bufA);
  __syncthreads();
  if (wid == 0) {
    add_buf(bufA);
    float* op = out + ((size_t)b * T_ + qb) * HS_;
#pragma unroll
    for (int rt = 0; rt < 2; ++rt)
#pragma unroll
      for (int db = 0; db < 8; ++db) {
        f32x4 v = acc[rt][db] * linv[rt];
        *reinterpret_cast<f32x4*>(op + (size_t)(rt * 16 + c) * HS_ + db * 16 + 4 * g) = v;
      }
  }
}

// ---------------------------------------------------------------------------
extern "C" void kernel_launch(void* const* d_in, const int* in_sizes, int n_in,
                              void* d_out, int out_size, void* d_ws, size_t ws_size,
                              hipStream_t stream) {
  const float* x  = (const float*)d_in[0];
  const float* Wk = (const float*)d_in[1];
  const float* Wq = (const float*)d_in[2];
  const float* Wv = (const float*)d_in[3];
  float* out = (float*)d_out;

  char* ws = (char*)d_ws;
  __bf16* Wt = (__bf16*)ws;                              // 768 KiB
  __bf16* Qf = (__bf16*)(ws + 786432);                   // 4 MiB (fragment-tiled)
  __bf16* Kf = (__bf16*)(ws + 786432 + 4194304);         // 4 MiB (fragment-tiled)
  __bf16* Vf = (__bf16*)(ws + 786432 + 8388608);         // 4 MiB (fragment-tiled)

  prep_w_kernel<<<48, 256, 0, stream>>>(Wk, Wq, Wv, Wt);
  proj_kernel<<<512, 256, 0, stream>>>(x, Wt, Qf, Kf, Vf);
  attn_kernel<<<512, 256, 0, stream>>>(Qf, Kf, Vf, out);
}

// Round 10
// 86.195 us; speedup vs baseline: 1.7266x; 1.0324x over previous
//
#include <hip/hip_runtime.h>
#include <hip/hip_bf16.h>
#include <math.h>

#define B_  4
#define T_  4096
#define C_  1024
#define HS_ 128

using bf16x8 = __attribute__((ext_vector_type(8))) __bf16;
using bf16x4 = __attribute__((ext_vector_type(4))) __bf16;
using f32x4  = __attribute__((ext_vector_type(4))) float;

#define MFMA(a, b, c) __builtin_amdgcn_mfma_f32_16x16x32_bf16(a, b, c, 0, 0, 0)

typedef __attribute__((address_space(1))) const float gfloat;
typedef __attribute__((address_space(3))) float lfloat;

// fast exp2 via v_exp_f32; trailing s_nop covers the 1-wait-state trans hazard
__device__ inline float fexp2(float x) {
  float r;
  asm volatile("v_exp_f32 %0, %1\n\ts_nop 0" : "=v"(r) : "v"(x));
  return r;
}

// ---------------------------------------------------------------------------
// Fragment-tiled layouts (R8/R9: attn loads were 32-64 cache-line gathers ->
// ~16x request amplification; tiling Q/K/V per 32-row tile in exact
// [chunk][lane][8 bf16] MFMA order made every attn load one 1KB block and
// cut attn 69 -> ~25us):
//   Qf[b*128+t][j=rt*4+cs][l][e] = Q[t*32 + rt*16 + (l&15)][cs*32+(l>>4)*8+e]
//   Kf[b*128+t][j=2cs+hi ][l][e] = K[t*32 + kp(l&15)+4hi   ][cs*32+(l>>4)*8+e]
//   Vf[b*128+t][j=db     ][l][e] = V[t*32 + (l>>4)*8+e     ][db*16 + (l&15)]
// (kp(c)=((c&12)<<1)|(c&3)).
// ---------------------------------------------------------------------------

// ---------------------------------------------------------------------------
// Kernel 1: W fp32 [1024][128] -> Wt bf16 [3][128][1024] via LDS transpose.
// m=0: Wq scaled by 1/sqrt(128) * log2(e)  (exp2-domain softmax).
// ---------------------------------------------------------------------------
__global__ __launch_bounds__(256) void prep_w_kernel(
    const float* __restrict__ Wk, const float* __restrict__ Wq,
    const float* __restrict__ Wv, __bf16* __restrict__ Wt) {
  const int m  = blockIdx.x >> 4;        // 0..2
  const int k0 = (blockIdx.x & 15) * 64; // k-slab base
  const float* W = (m == 0) ? Wq : ((m == 1) ? Wk : Wv);
  const float scale = (m == 0) ? (0.08838834764831845f * 1.4426950408889634f) : 1.0f;
  __shared__ __bf16 tile[128][72];       // [n][k-within-slab], padded
  const int t = threadIdx.x;
#pragma unroll
  for (int p = 0; p < 8; ++p) {
    int e  = p * 1024 + t * 4;
    int r  = e >> 7;                     // 0..63
    int cc = e & 127;
    float4 w = *reinterpret_cast<const float4*>(&W[(size_t)(k0 + r) * HS_ + cc]);
    tile[cc + 0][r] = (__bf16)(w.x * scale);
    tile[cc + 1][r] = (__bf16)(w.y * scale);
    tile[cc + 2][r] = (__bf16)(w.z * scale);
    tile[cc + 3][r] = (__bf16)(w.w * scale);
  }
  __syncthreads();
#pragma unroll
  for (int p = 0; p < 4; ++p) {
    int e  = p * 2048 + t * 8;
    int n  = e >> 6;                     // 0..127
    int kk = e & 63;
    bf16x8 v;
#pragma unroll
    for (int jj = 0; jj < 8; ++jj) v[jj] = tile[n][kk + jj];
    *reinterpret_cast<bf16x8*>(&Wt[((size_t)m * 128 + n) * C_ + k0 + kk]) = v;
  }
}

__device__ inline bf16x8 cvt8p(float4 u, float4 v) {
  bf16x8 r;
  r[0] = (__bf16)u.x; r[1] = (__bf16)u.y; r[2] = (__bf16)u.z; r[3] = (__bf16)u.w;
  r[4] = (__bf16)v.x; r[5] = (__bf16)v.y; r[6] = (__bf16)v.z; r[7] = (__bf16)v.w;
  return r;
}

// ---------------------------------------------------------------------------
// Kernel 2: projections. R9 post-mortem: per-t-step W loads (24 L2 hits,
// ~300cyc latency) had only 1-ksub lookahead -> every ksub stalled on L2
// with just 2 waves/SIMD to cover. R10 changes:
//  * W BURST: all 24 W fragments of the t-step loaded in one issue burst
//    (96 VGPR) before compute -> L2 latency paid once per t-step,
//  * 2-deep x staging: TRIPLE buffer (48KB LDS), stage(t+2) issued after
//    the W burst, end-of-iter counted s_waitcnt vmcnt(4) (guarantees
//    stage(t+1) only; W loads already drained by per-MFMA compiler waits
//    since they are older than the stage). t-loop fully unrolled so the
//    tail uses vmcnt(0) statically.
// Staging swizzle unchanged (chunk^=row&15 both sides; 0 conflicts R5-R9).
// Epilogue: fragment-tiled Q/K/V stores (see layout comment above).
// ---------------------------------------------------------------------------
__global__ __launch_bounds__(256) void proj_kernel(
    const float* __restrict__ x, const __bf16* __restrict__ Wt,
    __bf16* __restrict__ Qf, __bf16* __restrict__ Kf, __bf16* __restrict__ Vf) {
  __shared__ float xs[3][32 * 128];      // 48 KB
  const int tid = threadIdx.x;
  const int wid = tid >> 6;      // 0..3
  const int l   = tid & 63;
  const int c   = l & 15;        // A-row / B-col slot
  const int g   = l >> 4;        // k-group
  const int rbase = blockIdx.x * 32;
  const size_t tile = blockIdx.x;          // global tile = b*128 + (t>>5)

  f32x4 acc[6][2];
#pragma unroll
  for (int i = 0; i < 6; ++i) { acc[i][0] = 0.f; acc[i][1] = 0.f; }

  const __bf16* wb[6];
#pragma unroll
  for (int i = 0; i < 6; ++i) {
    int u = wid * 6 + i;
    wb[i] = Wt + ((size_t)(u >> 3) * 128 + (u & 7) * 16 + c) * C_ + g * 8;
  }

  // staging: tile 32 rows x 32 chunks(16B). wave w instr k2 lane l ->
  // dest chunk w*256+k2*64+l (linear); row = w*8+k2*2+(l>>5); p=l&31;
  // source chunk-in-row = p ^ (row&15) (same involution applied on read).
  const int row00 = wid * 8 + (l >> 5);
  const int p_in  = l & 31;
  const float* gs[4];
#pragma unroll
  for (int k2 = 0; k2 < 4; ++k2) {
    int row = row00 + 2 * k2;
    gs[k2] = x + (size_t)(rbase + row) * C_ + (p_in ^ (row & 15)) * 4;
  }

  auto stage = [&](int t, int buf) {
#pragma unroll
    for (int k2 = 0; k2 < 4; ++k2)
      __builtin_amdgcn_global_load_lds((gfloat*)(gs[k2] + t * 128),
          (lfloat*)&xs[buf][wid * 1024 + k2 * 256], 16, 0, 0);
  };

  stage(0, 0);
  stage(1, 1);
  asm volatile("s_waitcnt vmcnt(4)" ::: "memory");   // stage(0) complete
  __syncthreads();

#pragma unroll
  for (int t = 0; t < 8; ++t) {
    const int cur = t % 3;
    const int nxt = (t + 2) % 3;

    // ---- W burst: all 24 fragments for this K-step (issued FIRST so the
    // trailing counted vmcnt never has to wait on them) ----
    bf16x8 w[6][4];
#pragma unroll
    for (int ksub = 0; ksub < 4; ++ksub)
#pragma unroll
      for (int i = 0; i < 6; ++i)
        w[i][ksub] = *reinterpret_cast<const bf16x8*>(wb[i] + t * 128 + ksub * 32);

    // ---- 2-deep x prefetch ----
    if (t + 2 < 8) stage(t + 2, nxt);

    const float* xt = &xs[cur][0];
#pragma unroll
    for (int ksub = 0; ksub < 4; ++ksub) {
#pragma unroll
      for (int rt = 0; rt < 2; ++rt) {
        const int rr = rt * 16 + c;          // rr & 15 == c
        const int q  = ksub * 8 + g * 2;     // 16B-chunk index pair (q, q+1)
        float4 lo = *reinterpret_cast<const float4*>(&xt[rr * 128 + ((q ^ c) << 2)]);
        float4 hi = *reinterpret_cast<const float4*>(&xt[rr * 128 + (((q + 1) ^ c) << 2)]);
        bf16x8 a = cvt8p(lo, hi);
#pragma unroll
        for (int i = 0; i < 6; ++i) acc[i][rt] = MFMA(a, w[i][ksub], acc[i][rt]);
      }
    }
    // counted wait: only stage(t+1) must be complete; stage(t+2)'s 4 loads
    // may stay in flight. Tail iterations drain fully.
    if (t + 2 < 8) {
      asm volatile("s_waitcnt vmcnt(4)" ::: "memory");
    } else {
      asm volatile("s_waitcnt vmcnt(0)" ::: "memory");
    }
    __syncthreads();
  }

  // ---- epilogue: fragment-tiled stores ----
#pragma unroll
  for (int i = 0; i < 6; ++i) {
    const int u = wid * 6 + i;
    const int m = u >> 3, nt = u & 7;
    const int gprime = ((nt & 1) << 1) + (c >> 3);  // col-group (l'>>4)
    const int e = c & 7;
    if (m == 0) {
      // j = rt*4 + (nt>>1); l' = gprime*16 + (4g+rr)
#pragma unroll
      for (int rt = 0; rt < 2; ++rt)
#pragma unroll
        for (int rr = 0; rr < 4; ++rr)
          Qf[(tile * 8 + rt * 4 + (nt >> 1)) * 512 +
             (gprime * 16 + 4 * g + rr) * 8 + e] = (__bf16)acc[i][rt][rr];
    } else if (m == 1) {
      // rho = rt*16+4g+rr: hi = g&1; c'' = ((2rt+(g>>1))<<2)|rr
#pragma unroll
      for (int rt = 0; rt < 2; ++rt)
#pragma unroll
        for (int rr = 0; rr < 4; ++rr)
          Kf[(tile * 8 + 2 * (nt >> 1) + (g & 1)) * 512 +
             (gprime * 16 + (((2 * rt + (g >> 1)) << 2) | rr)) * 8 + e] =
              (__bf16)acc[i][rt][rr];
    } else {
      // j = nt; l' = (2rt+(g>>1))*16 + c; e = 4(g&1)+rr (contiguous in rr)
#pragma unroll
      for (int rt = 0; rt < 2; ++rt) {
        bf16x4 v4;
#pragma unroll
        for (int rr = 0; rr < 4; ++rr) v4[rr] = (__bf16)acc[i][rt][rr];
        *reinterpret_cast<bf16x4*>(
            Vf + (tile * 8 + nt) * 512 +
            ((2 * rt + (g >> 1)) * 16 + c) * 8 + 4 * (g & 1)) = v4;
      }
    }
  }
}

// ---------------------------------------------------------------------------
// Kernel 3: causal flash attention. 4 waves/block; each wave owns the FULL
// 32 q-rows (acc[2][8]) with 4-way kt split. All Q/K/V global loads are
// fragment-tiled: base + chunk*512 + l*8 -> perfectly coalesced 1KB blocks.
// S^T = mfma(K_perm, Q^T); P per-lane IS the PV B-fragment. Per-lane softmax
// gate (__all), lrun per-lane partial reduced once at wave end. exp2 domain.
// ---------------------------------------------------------------------------
__global__ __launch_bounds__(256, 2) void attn_kernel(
    const __bf16* __restrict__ Qf, const __bf16* __restrict__ Kf,
    const __bf16* __restrict__ Vf, float* __restrict__ out) {
  __shared__ float sm[4][32];
  __shared__ float sl[4][32];
  __shared__ float bufA[32][132];
  __shared__ float bufB[32][132];

  const int tid = threadIdx.x;
  const int wid = tid >> 6;
  const int l   = tid & 63;
  const int c   = l & 15;
  const int g   = l >> 4;
  const int bid = blockIdx.x;
  const int b   = (bid & 7) >> 1;                    // XCD-affine batch
  const int j   = ((bid >> 3) << 1) | (bid & 1);     // 0..127
  const int qt  = (j < 64) ? (127 - j) : (j - 64);   // big tiles dispatched first
  const int qb  = qt * 32;

  bf16x8 qf[2][4];
  {
    const __bf16* Qt = Qf + (size_t)(b * 128 + qt) * 4096 + l * 8;
#pragma unroll
    for (int rt = 0; rt < 2; ++rt)
#pragma unroll
      for (int cs = 0; cs < 4; ++cs)
        qf[rt][cs] = *reinterpret_cast<const bf16x8*>(Qt + (rt * 4 + cs) * 512);
  }

  f32x4 acc[2][8];
#pragma unroll
  for (int i = 0; i < 2; ++i)
#pragma unroll
    for (int d = 0; d < 8; ++d) acc[i][d] = 0.f;
  float mrun[2] = {-INFINITY, -INFINITY};
  float lrun[2] = {0.f, 0.f};   // PER-LANE partial sums (reduced at wave end)

  if (wid <= qt) {
    const __bf16* Kb8 = Kf + (size_t)b * 128 * 4096 + l * 8;
    const __bf16* Vb8 = Vf + (size_t)b * 128 * 4096 + l * 8;
    bf16x8 kreg[8];
    auto kload = [&](int kt) {
      const __bf16* kb = Kb8 + (size_t)kt * 4096;
#pragma unroll
      for (int jj = 0; jj < 8; ++jj)
        kreg[jj] = *reinterpret_cast<const bf16x8*>(kb + jj * 512);
    };
    kload(wid);

    for (int kt = wid; kt <= qt; kt += 4) {
      f32x4 s00 = 0.f, s01 = 0.f, s10 = 0.f, s11 = 0.f;
      __builtin_amdgcn_s_setprio(1);
#pragma unroll
      for (int cs = 0; cs < 4; ++cs) {
        s00 = MFMA(kreg[2 * cs], qf[0][cs], s00);
        s01 = MFMA(kreg[2 * cs + 1], qf[0][cs], s01);
        s10 = MFMA(kreg[2 * cs], qf[1][cs], s10);
        s11 = MFMA(kreg[2 * cs + 1], qf[1][cs], s11);
      }
      __builtin_amdgcn_s_setprio(0);

      bf16x8 vf[8];
      {
        const __bf16* vb = Vb8 + (size_t)kt * 4096;
#pragma unroll
        for (int db = 0; db < 8; ++db)
          vf[db] = *reinterpret_cast<const bf16x8*>(vb + db * 512);
      }

      if (kt + 4 <= qt) kload(kt + 4);        // prefetch next K tile

      const bool maskt = (kt == qt);           // only the diagonal tile
      bf16x8 pb[2];
#pragma unroll
      for (int rt = 0; rt < 2; ++rt) {
        float p[8];
        const f32x4 sa = rt ? s10 : s00;
        const f32x4 sb = rt ? s11 : s01;
#pragma unroll
        for (int rr = 0; rr < 4; ++rr) { p[rr] = sa[rr]; p[4 + rr] = sb[rr]; }
        if (maskt) {
          const int lim = rt * 16 + c;
#pragma unroll
          for (int jj = 0; jj < 8; ++jj)
            if (8 * g + jj > lim) p[jj] = -INFINITY;
        }
        // per-lane max only (no cross-lane on the common path)
        float t0 = fmaxf(fmaxf(p[0], p[1]), p[2]);
        float t1 = fmaxf(fmaxf(p[3], p[4]), p[5]);
        float t2 = fmaxf(fmaxf(p[6], p[7]), t0);
        float tmax = fmaxf(t1, t2);

        if (!__all(tmax <= mrun[rt] + 11.5415603f)) {   // rare: defer-max fired
          float cmax = fmaxf(tmax, __shfl_xor(tmax, 16));
          cmax = fmaxf(cmax, __shfl_xor(cmax, 32));     // column max (over g)
          float mnew = fmaxf(mrun[rt], cmax);
          float al   = fexp2(mrun[rt] - mnew);
          mrun[rt] = mnew;
          lrun[rt] *= al;
#pragma unroll
          for (int db = 0; db < 8; ++db) acc[rt][db] *= al;
        }
        const float mc = mrun[rt];
#pragma unroll
        for (int jj = 0; jj < 8; ++jj) p[jj] = fexp2(p[jj] - mc);
        lrun[rt] += ((p[0] + p[1]) + (p[2] + p[3])) + ((p[4] + p[5]) + (p[6] + p[7]));
#pragma unroll
        for (int jj = 0; jj < 8; ++jj) pb[rt][jj] = (__bf16)p[jj];
      }

      __builtin_amdgcn_s_setprio(1);
#pragma unroll
      for (int db = 0; db < 8; ++db) {
        acc[0][db] = MFMA(vf[db], pb[0], acc[0][db]);
        acc[1][db] = MFMA(vf[db], pb[1], acc[1][db]);
      }
      __builtin_amdgcn_s_setprio(0);
    }
  }

  // wave-end: reduce per-lane l partials across the 4 g-lanes of each column
#pragma unroll
  for (int rt = 0; rt < 2; ++rt) {
    lrun[rt] += __shfl_xor(lrun[rt], 16);
    lrun[rt] += __shfl_xor(lrun[rt], 32);
  }

  // ---- combine the 4 waves' partial (m, l, O) ----
  if (g == 0) {
    sm[wid][c] = mrun[0]; sm[wid][16 + c] = mrun[1];
    sl[wid][c] = lrun[0]; sl[wid][16 + c] = lrun[1];
  }
  __syncthreads();

  float linv[2];
#pragma unroll
  for (int rt = 0; rt < 2; ++rt) {
    const int q = rt * 16 + c;
    float ms = fmaxf(fmaxf(sm[0][q], sm[1][q]), fmaxf(sm[2][q], sm[3][q]));
    float ls = fexp2(sm[0][q] - ms) * sl[0][q] + fexp2(sm[1][q] - ms) * sl[1][q]
             + fexp2(sm[2][q] - ms) * sl[2][q] + fexp2(sm[3][q] - ms) * sl[3][q];
    float al = fexp2(mrun[rt] - ms);
#pragma unroll
    for (int db = 0; db < 8; ++db) acc[rt][db] *= al;
    linv[rt] = 1.0f / ls;
  }

  auto store_buf = [&](float(*buf)[132]) {
#pragma unroll
    for (int rt = 0; rt < 2; ++rt)
#pragma unroll
      for (int db = 0; db < 8; ++db)
        *reinterpret_cast<f32x4*>(&buf[rt * 16 + c][db * 16 + 4 * g]) = acc[rt][db];
  };
  auto add_buf = [&](float(*buf)[132]) {
#pragma unroll
    for (int rt = 0; rt < 2; ++rt)
#pragma unroll
      for (int db = 0; db < 8; ++db)
        acc[rt][db] += *reinterpret_cast<const f32x4*>(&buf[rt * 16 + c][db * 16 + 4 * g]);
  };

  if (wid == 2) store_buf(bufA);
  if (wid == 3) store_buf(bufB);
  __syncthreads();
  if (wid == 0) add_buf(bufA);
  if (wid == 1) add_buf(bufB);
  __syncthreads();
  if (wid == 1) store_buf(bufA);
  __syncthreads();
  if (wid == 0) {
    add_buf(bufA);
    float* op = out + ((size_t)b * T_ + qb) * HS_;
#pragma unroll
    for (int rt = 0; rt < 2; ++rt)
#pragma unroll
      for (int db = 0; db < 8; ++db) {
        f32x4 v = acc[rt][db] * linv[rt];
        *reinterpret_cast<f32x4*>(op + (size_t)(rt * 16 + c) * HS_ + db * 16 + 4 * g) = v;
      }
  }
}

// ---------------------------------------------------------------------------
extern "C" void kernel_launch(void* const* d_in, const int* in_sizes, int n_in,
                              void* d_out, int out_size, void* d_ws, size_t ws_size,
                              hipStream_t stream) {
  const float* x  = (const float*)d_in[0];
  const float* Wk = (const float*)d_in[1];
  const float* Wq = (const float*)d_in[2];
  const float* Wv = (const float*)d_in[3];
  float* out = (float*)d_out;

  char* ws = (char*)d_ws;
  __bf16* Wt = (__bf16*)ws;                              // 768 KiB
  __bf16* Qf = (__bf16*)(ws + 786432);                   // 4 MiB (fragment-tiled)
  __bf16* Kf = (__bf16*)(ws + 786432 + 4194304);         // 4 MiB (fragment-tiled)
  __bf16* Vf = (__bf16*)(ws + 786432 + 8388608);         // 4 MiB (fragment-tiled)

  prep_w_kernel<<<48, 256, 0, stream>>>(Wk, Wq, Wv, Wt);
  proj_kernel<<<512, 256, 0, stream>>>(x, Wt, Qf, Kf, Vf);
  attn_kernel<<<512, 256, 0, stream>>>(Qf, Kf, Vf, out);
}

// Round 11
// 73.642 us; speedup vs baseline: 2.0210x; 1.1705x over previous
//
#include <hip/hip_runtime.h>
#include <hip/hip_bf16.h>
#include <math.h>

#define B_  4
#define T_  4096
#define C_  1024
#define HS_ 128

using bf16x8 = __attribute__((ext_vector_type(8))) __bf16;
using bf16x4 = __attribute__((ext_vector_type(4))) __bf16;
using f32x4  = __attribute__((ext_vector_type(4))) float;

#define MFMA(a, b, c) __builtin_amdgcn_mfma_f32_16x16x32_bf16(a, b, c, 0, 0, 0)

typedef __attribute__((address_space(1))) const float gfloat;
typedef __attribute__((address_space(3))) float lfloat;

// fast exp2 via v_exp_f32; trailing s_nop covers the 1-wait-state trans hazard
__device__ inline float fexp2(float x) {
  float r;
  asm volatile("v_exp_f32 %0, %1\n\ts_nop 0" : "=v"(r) : "v"(x));
  return r;
}

// ---------------------------------------------------------------------------
// Fragment-tiled layouts (R8/R9: attn loads were 32-64 cache-line gathers ->
// ~16x request amplification; tiling Q/K/V per 32-row tile in exact
// [chunk][lane][8 bf16] MFMA order made every attn load one 1KB block):
//   Qf[b*128+t][j=rt*4+cs][l][e] = Q[t*32 + rt*16 + (l&15)][cs*32+(l>>4)*8+e]
//   Kf[b*128+t][j=2cs+hi ][l][e] = K[t*32 + kp(l&15)+4hi   ][cs*32+(l>>4)*8+e]
//   Vf[b*128+t][j=db     ][l][e] = V[t*32 + (l>>4)*8+e     ][db*16 + (l&15)]
// (kp(c)=((c&12)<<1)|(c&3)).
// ---------------------------------------------------------------------------

// ---------------------------------------------------------------------------
// Kernel 1: W fp32 [1024][128] -> Wt bf16 [3][128][1024] via LDS transpose.
// m=0: Wq scaled by 1/sqrt(128) * log2(e)  (exp2-domain softmax).
// ---------------------------------------------------------------------------
__global__ __launch_bounds__(256) void prep_w_kernel(
    const float* __restrict__ Wk, const float* __restrict__ Wq,
    const float* __restrict__ Wv, __bf16* __restrict__ Wt) {
  const int m  = blockIdx.x >> 4;        // 0..2
  const int k0 = (blockIdx.x & 15) * 64; // k-slab base
  const float* W = (m == 0) ? Wq : ((m == 1) ? Wk : Wv);
  const float scale = (m == 0) ? (0.08838834764831845f * 1.4426950408889634f) : 1.0f;
  __shared__ __bf16 tile[128][72];       // [n][k-within-slab], padded
  const int t = threadIdx.x;
#pragma unroll
  for (int p = 0; p < 8; ++p) {
    int e  = p * 1024 + t * 4;
    int r  = e >> 7;                     // 0..63
    int cc = e & 127;
    float4 w = *reinterpret_cast<const float4*>(&W[(size_t)(k0 + r) * HS_ + cc]);
    tile[cc + 0][r] = (__bf16)(w.x * scale);
    tile[cc + 1][r] = (__bf16)(w.y * scale);
    tile[cc + 2][r] = (__bf16)(w.z * scale);
    tile[cc + 3][r] = (__bf16)(w.w * scale);
  }
  __syncthreads();
#pragma unroll
  for (int p = 0; p < 4; ++p) {
    int e  = p * 2048 + t * 8;
    int n  = e >> 6;                     // 0..127
    int kk = e & 63;
    bf16x8 v;
#pragma unroll
    for (int jj = 0; jj < 8; ++jj) v[jj] = tile[n][kk + jj];
    *reinterpret_cast<bf16x8*>(&Wt[((size_t)m * 128 + n) * C_ + k0 + kk]) = v;
  }
}

__device__ inline bf16x8 cvt8p(float4 u, float4 v) {
  bf16x8 r;
  r[0] = (__bf16)u.x; r[1] = (__bf16)u.y; r[2] = (__bf16)u.z; r[3] = (__bf16)u.w;
  r[4] = (__bf16)v.x; r[5] = (__bf16)v.y; r[6] = (__bf16)v.z; r[7] = (__bf16)v.w;
  return r;
}

// ---------------------------------------------------------------------------
// Kernel 2: projections. R10 post-mortem: register-staged W was defeated by
// the allocator a 3rd time (VGPR=88 < the 96 needed; loads rematerialized at
// use -> un-hidden L2 chains). R11: W goes through LDS via global_load_lds
// (DMA, no VGPRs, latency carried by vmcnt) like x.
//   Block = 64 rows x 384 cols, 8 waves (2 row x 4 col), grid 256 = 1/CU.
//   K-step 32: x tile 64x32 fp32 = 8 KB, W tile 384x32 bf16 = 24 KB.
//   TRIPLE buffered (96 KB LDS): stage(t+2) issued before compute(t);
//   end-of-iter counted vmcnt(4) -> stage(t+1) landed, stage(t+2) in flight
//   across the barrier (T4). HBM x-stream (~67 MB) is the floor (~11 us).
// Swizzles (both-sides, rule #21): x chunk^=(row&7), W chunk^=(col&3);
// slot-group analysis: uniform 8 lanes per 4-bank group = conflict-free.
// Epilogue: fragment-tiled Q/K/V stores, tile = bid*2 + wr.
// ---------------------------------------------------------------------------
__global__ __launch_bounds__(512) void proj_kernel(
    const float* __restrict__ x, const __bf16* __restrict__ Wt,
    __bf16* __restrict__ Qf, __bf16* __restrict__ Kf, __bf16* __restrict__ Vf) {
  __shared__ __align__(16) char lds[98304];   // 3 x (8 KB x + 24 KB W)
  const int tid = threadIdx.x;
  const int wid = tid >> 6;      // 0..7
  const int l   = tid & 63;
  const int c   = l & 15;        // A-row / B-col slot
  const int g   = l >> 4;        // k-group
  const int wr  = wid >> 2;      // wave row (0..1): rows wr*32..wr*32+31
  const int wc  = wid & 3;       // wave col (0..3): units wc*6..wc*6+5
  const int rbase = blockIdx.x * 64;

  f32x4 acc[6][2];
#pragma unroll
  for (int i = 0; i < 6; ++i) { acc[i][0] = 0.f; acc[i][1] = 0.f; }

  // ---- staging source/dest precompute ----
  // x: 8 KB = 512 chunks(16B); thread t -> row=t>>3, ch=t&7 (linear dest),
  //    global source chunk = ch ^ (row&7)  [inverse swizzle]
  const int xrow = tid >> 3;
  const int xch  = tid & 7;
  const float* xsrc = x + (size_t)(rbase + xrow) * C_ + ((xch ^ (xrow & 7)) << 2);
  // W: 24 KB = 1536 chunks; instr i, thread t -> id=i*512+t, col=id>>2,
  //    kc=id&3 (linear dest), source kchunk = kc ^ (col&3)
  const __bf16* wsrc[3];
  int wdst[3];
#pragma unroll
  for (int i = 0; i < 3; ++i) {
    int id2 = i * 512 + tid;
    int cg  = id2 >> 2;
    int kc  = id2 & 3;
    wsrc[i] = Wt + (size_t)cg * C_ + ((kc ^ (cg & 3)) << 3);
    wdst[i] = 8192 + id2 * 16;
  }

  auto stage = [&](int t, int bo) {
    __builtin_amdgcn_global_load_lds((gfloat*)(xsrc + t * 32),
        (lfloat*)(lds + bo + tid * 16), 16, 0, 0);
#pragma unroll
    for (int i = 0; i < 3; ++i)
      __builtin_amdgcn_global_load_lds((gfloat*)(wsrc[i] + t * 32),
          (lfloat*)(lds + bo + wdst[i]), 16, 0, 0);
  };

  // B-frag LDS byte offsets (within W region) and A-frag row bases
  int woffs[6];
#pragma unroll
  for (int i = 0; i < 6; ++i) {
    int u  = wc * 6 + i;
    int cg = (u >> 3) * 128 + (u & 7) * 16 + c;
    woffs[i] = 8192 + cg * 64 + ((g ^ (cg & 3)) << 4);
  }
  int xoffs[2][2];
#pragma unroll
  for (int rt = 0; rt < 2; ++rt) {
    int row = wr * 32 + rt * 16 + c;
#pragma unroll
    for (int j = 0; j < 2; ++j)
      xoffs[rt][j] = row * 128 + ((((g << 1) | j) ^ (row & 7)) << 4);
  }

  stage(0, 0);
  stage(1, 32768);
  asm volatile("s_waitcnt vmcnt(4)" ::: "memory");   // stage(0) complete
  __syncthreads();

  int b0 = 0, b1 = 32768, b2 = 65536;
  for (int t = 0; t < 32; ++t) {
    const bool more = (t + 2 < 32);
    if (more) stage(t + 2, b2);

    // ---- compute from buffer b0 ----
    bf16x8 wf[6];
#pragma unroll
    for (int i = 0; i < 6; ++i)
      wf[i] = *reinterpret_cast<const bf16x8*>(lds + b0 + woffs[i]);
#pragma unroll
    for (int rt = 0; rt < 2; ++rt) {
      float4 lo = *reinterpret_cast<const float4*>(lds + b0 + xoffs[rt][0]);
      float4 hi = *reinterpret_cast<const float4*>(lds + b0 + xoffs[rt][1]);
      bf16x8 a = cvt8p(lo, hi);
#pragma unroll
      for (int i = 0; i < 6; ++i) acc[i][rt] = MFMA(a, wf[i], acc[i][rt]);
    }

    if (more) {
      asm volatile("s_waitcnt vmcnt(4)" ::: "memory");  // stage(t+1) landed
    } else {
      asm volatile("s_waitcnt vmcnt(0)" ::: "memory");
    }
    __syncthreads();
    int tmp = b0; b0 = b1; b1 = b2; b2 = tmp;
  }

  // ---- epilogue: fragment-tiled stores (tile = bid*2 + wr) ----
  const size_t tile2 = (size_t)blockIdx.x * 2 + wr;
#pragma unroll
  for (int i = 0; i < 6; ++i) {
    const int u = wc * 6 + i;
    const int m = u >> 3, nt = u & 7;
    const int gprime = ((nt & 1) << 1) + (c >> 3);  // col-group (l'>>4)
    const int e = c & 7;
    if (m == 0) {
      // j = rt*4 + (nt>>1); l' = gprime*16 + (4g+rr)
#pragma unroll
      for (int rt = 0; rt < 2; ++rt)
#pragma unroll
        for (int rr = 0; rr < 4; ++rr)
          Qf[(tile2 * 8 + rt * 4 + (nt >> 1)) * 512 +
             (gprime * 16 + 4 * g + rr) * 8 + e] = (__bf16)acc[i][rt][rr];
    } else if (m == 1) {
      // rho = rt*16+4g+rr: hi = g&1; c'' = ((2rt+(g>>1))<<2)|rr
#pragma unroll
      for (int rt = 0; rt < 2; ++rt)
#pragma unroll
        for (int rr = 0; rr < 4; ++rr)
          Kf[(tile2 * 8 + 2 * (nt >> 1) + (g & 1)) * 512 +
             (gprime * 16 + (((2 * rt + (g >> 1)) << 2) | rr)) * 8 + e] =
              (__bf16)acc[i][rt][rr];
    } else {
      // j = nt; l' = (2rt+(g>>1))*16 + c; e = 4(g&1)+rr (contiguous in rr)
#pragma unroll
      for (int rt = 0; rt < 2; ++rt) {
        bf16x4 v4;
#pragma unroll
        for (int rr = 0; rr < 4; ++rr) v4[rr] = (__bf16)acc[i][rt][rr];
        *reinterpret_cast<bf16x4*>(
            Vf + (tile2 * 8 + nt) * 512 +
            ((2 * rt + (g >> 1)) * 16 + c) * 8 + 4 * (g & 1)) = v4;
      }
    }
  }
}

// ---------------------------------------------------------------------------
// Kernel 3: causal flash attention. 4 waves/block; each wave owns the FULL
// 32 q-rows (acc[2][8]) with 4-way kt split. All Q/K/V global loads are
// fragment-tiled: base + chunk*512 + l*8 -> perfectly coalesced 1KB blocks.
// S^T = mfma(K_perm, Q^T); P per-lane IS the PV B-fragment. Per-lane softmax
// gate (__all), lrun per-lane partial reduced once at wave end. exp2 domain.
// ---------------------------------------------------------------------------
__global__ __launch_bounds__(256, 2) void attn_kernel(
    const __bf16* __restrict__ Qf, const __bf16* __restrict__ Kf,
    const __bf16* __restrict__ Vf, float* __restrict__ out) {
  __shared__ float sm[4][32];
  __shared__ float sl[4][32];
  __shared__ float bufA[32][132];
  __shared__ float bufB[32][132];

  const int tid = threadIdx.x;
  const int wid = tid >> 6;
  const int l   = tid & 63;
  const int c   = l & 15;
  const int g   = l >> 4;
  const int bid = blockIdx.x;
  const int b   = (bid & 7) >> 1;                    // XCD-affine batch
  const int j   = ((bid >> 3) << 1) | (bid & 1);     // 0..127
  const int qt  = (j < 64) ? (127 - j) : (j - 64);   // big tiles dispatched first
  const int qb  = qt * 32;

  bf16x8 qf[2][4];
  {
    const __bf16* Qt = Qf + (size_t)(b * 128 + qt) * 4096 + l * 8;
#pragma unroll
    for (int rt = 0; rt < 2; ++rt)
#pragma unroll
      for (int cs = 0; cs < 4; ++cs)
        qf[rt][cs] = *reinterpret_cast<const bf16x8*>(Qt + (rt * 4 + cs) * 512);
  }

  f32x4 acc[2][8];
#pragma unroll
  for (int i = 0; i < 2; ++i)
#pragma unroll
    for (int d = 0; d < 8; ++d) acc[i][d] = 0.f;
  float mrun[2] = {-INFINITY, -INFINITY};
  float lrun[2] = {0.f, 0.f};   // PER-LANE partial sums (reduced at wave end)

  if (wid <= qt) {
    const __bf16* Kb8 = Kf + (size_t)b * 128 * 4096 + l * 8;
    const __bf16* Vb8 = Vf + (size_t)b * 128 * 4096 + l * 8;
    bf16x8 kreg[8];
    auto kload = [&](int kt) {
      const __bf16* kb = Kb8 + (size_t)kt * 4096;
#pragma unroll
      for (int jj = 0; jj < 8; ++jj)
        kreg[jj] = *reinterpret_cast<const bf16x8*>(kb + jj * 512);
    };
    kload(wid);

    for (int kt = wid; kt <= qt; kt += 4) {
      f32x4 s00 = 0.f, s01 = 0.f, s10 = 0.f, s11 = 0.f;
      __builtin_amdgcn_s_setprio(1);
#pragma unroll
      for (int cs = 0; cs < 4; ++cs) {
        s00 = MFMA(kreg[2 * cs], qf[0][cs], s00);
        s01 = MFMA(kreg[2 * cs + 1], qf[0][cs], s01);
        s10 = MFMA(kreg[2 * cs], qf[1][cs], s10);
        s11 = MFMA(kreg[2 * cs + 1], qf[1][cs], s11);
      }
      __builtin_amdgcn_s_setprio(0);

      bf16x8 vf[8];
      {
        const __bf16* vb = Vb8 + (size_t)kt * 4096;
#pragma unroll
        for (int db = 0; db < 8; ++db)
          vf[db] = *reinterpret_cast<const bf16x8*>(vb + db * 512);
      }

      if (kt + 4 <= qt) kload(kt + 4);        // prefetch next K tile

      const bool maskt = (kt == qt);           // only the diagonal tile
      bf16x8 pb[2];
#pragma unroll
      for (int rt = 0; rt < 2; ++rt) {
        float p[8];
        const f32x4 sa = rt ? s10 : s00;
        const f32x4 sb = rt ? s11 : s01;
#pragma unroll
        for (int rr = 0; rr < 4; ++rr) { p[rr] = sa[rr]; p[4 + rr] = sb[rr]; }
        if (maskt) {
          const int lim = rt * 16 + c;
#pragma unroll
          for (int jj = 0; jj < 8; ++jj)
            if (8 * g + jj > lim) p[jj] = -INFINITY;
        }
        // per-lane max only (no cross-lane on the common path)
        float t0 = fmaxf(fmaxf(p[0], p[1]), p[2]);
        float t1 = fmaxf(fmaxf(p[3], p[4]), p[5]);
        float t2 = fmaxf(fmaxf(p[6], p[7]), t0);
        float tmax = fmaxf(t1, t2);

        if (!__all(tmax <= mrun[rt] + 11.5415603f)) {   // rare: defer-max fired
          float cmax = fmaxf(tmax, __shfl_xor(tmax, 16));
          cmax = fmaxf(cmax, __shfl_xor(cmax, 32));     // column max (over g)
          float mnew = fmaxf(mrun[rt], cmax);
          float al   = fexp2(mrun[rt] - mnew);
          mrun[rt] = mnew;
          lrun[rt] *= al;
#pragma unroll
          for (int db = 0; db < 8; ++db) acc[rt][db] *= al;
        }
        const float mc = mrun[rt];
#pragma unroll
        for (int jj = 0; jj < 8; ++jj) p[jj] = fexp2(p[jj] - mc);
        lrun[rt] += ((p[0] + p[1]) + (p[2] + p[3])) + ((p[4] + p[5]) + (p[6] + p[7]));
#pragma unroll
        for (int jj = 0; jj < 8; ++jj) pb[rt][jj] = (__bf16)p[jj];
      }

      __builtin_amdgcn_s_setprio(1);
#pragma unroll
      for (int db = 0; db < 8; ++db) {
        acc[0][db] = MFMA(vf[db], pb[0], acc[0][db]);
        acc[1][db] = MFMA(vf[db], pb[1], acc[1][db]);
      }
      __builtin_amdgcn_s_setprio(0);
    }
  }

  // wave-end: reduce per-lane l partials across the 4 g-lanes of each column
#pragma unroll
  for (int rt = 0; rt < 2; ++rt) {
    lrun[rt] += __shfl_xor(lrun[rt], 16);
    lrun[rt] += __shfl_xor(lrun[rt], 32);
  }

  // ---- combine the 4 waves' partial (m, l, O) ----
  if (g == 0) {
    sm[wid][c] = mrun[0]; sm[wid][16 + c] = mrun[1];
    sl[wid][c] = lrun[0]; sl[wid][16 + c] = lrun[1];
  }
  __syncthreads();

  float linv[2];
#pragma unroll
  for (int rt = 0; rt < 2; ++rt) {
    const int q = rt * 16 + c;
    float ms = fmaxf(fmaxf(sm[0][q], sm[1][q]), fmaxf(sm[2][q], sm[3][q]));
    float ls = fexp2(sm[0][q] - ms) * sl[0][q] + fexp2(sm[1][q] - ms) * sl[1][q]
             + fexp2(sm[2][q] - ms) * sl[2][q] + fexp2(sm[3][q] - ms) * sl[3][q];
    float al = fexp2(mrun[rt] - ms);
#pragma unroll
    for (int db = 0; db < 8; ++db) acc[rt][db] *= al;
    linv[rt] = 1.0f / ls;
  }

  auto store_buf = [&](float(*buf)[132]) {
#pragma unroll
    for (int rt = 0; rt < 2; ++rt)
#pragma unroll
      for (int db = 0; db < 8; ++db)
        *reinterpret_cast<f32x4*>(&buf[rt * 16 + c][db * 16 + 4 * g]) = acc[rt][db];
  };
  auto add_buf = [&](float(*buf)[132]) {
#pragma unroll
    for (int rt = 0; rt < 2; ++rt)
#pragma unroll
      for (int db = 0; db < 8; ++db)
        acc[rt][db] += *reinterpret_cast<const f32x4*>(&buf[rt * 16 + c][db * 16 + 4 * g]);
  };

  if (wid == 2) store_buf(bufA);
  if (wid == 3) store_buf(bufB);
  __syncthreads();
  if (wid == 0) add_buf(bufA);
  if (wid == 1) add_buf(bufB);
  __syncthreads();
  if (wid == 1) store_buf(bufA);
  __syncthreads();
  if (wid == 0) {
    add_buf(bufA);
    float* op = out + ((size_t)b * T_ + qb) * HS_;
#pragma unroll
    for (int rt = 0; rt < 2; ++rt)
#pragma unroll
      for (int db = 0; db < 8; ++db) {
        f32x4 v = acc[rt][db] * linv[rt];
        *reinterpret_cast<f32x4*>(op + (size_t)(rt * 16 + c) * HS_ + db * 16 + 4 * g) = v;
      }
  }
}

// ---------------------------------------------------------------------------
extern "C" void kernel_launch(void* const* d_in, const int* in_sizes, int n_in,
                              void* d_out, int out_size, void* d_ws, size_t ws_size,
                              hipStream_t stream) {
  const float* x  = (const float*)d_in[0];
  const float* Wk = (const float*)d_in[1];
  const float* Wq = (const float*)d_in[2];
  const float* Wv = (const float*)d_in[3];
  float* out = (float*)d_out;

  char* ws = (char*)d_ws;
  __bf16* Wt = (__bf16*)ws;                              // 768 KiB
  __bf16* Qf = (__bf16*)(ws + 786432);                   // 4 MiB (fragment-tiled)
  __bf16* Kf = (__bf16*)(ws + 786432 + 4194304);         // 4 MiB (fragment-tiled)
  __bf16* Vf = (__bf16*)(ws + 786432 + 8388608);         // 4 MiB (fragment-tiled)

  prep_w_kernel<<<48, 256, 0, stream>>>(Wk, Wq, Wv, Wt);
  proj_kernel<<<256, 512, 0, stream>>>(x, Wt, Qf, Kf, Vf);
  attn_kernel<<<512, 256, 0, stream>>>(Qf, Kf, Vf, out);
}